// Round 1
// baseline (843.451 us; speedup 1.0000x reference)
//
#include <hip/hip_runtime.h>
#include <math.h>

#define BB 4
#define LL 1024
#define SS 1024
#define DM 1024
#define HH 16
#define DKH 64
#define NH 1024          // H*DKH
#define SM_SCALE 0.125f  // 1/sqrt(64)

// ---------------------------------------------------------------------------
// Projection: C[b][i][n] = sum_m A[b][i][m] * (gate[b][n][m]*W[n][m]) + bias[n]
// Tiles: BM=64, BN=64, BK=32. Block 256 threads, 4x4 micro-tile per thread.
// ---------------------------------------------------------------------------
__global__ __launch_bounds__(256) void proj_kernel(
    const float* __restrict__ A, const float* __restrict__ W,
    const float* __restrict__ gate, const float* __restrict__ bias,
    float* __restrict__ C)
{
    __shared__ float As[32][68];   // [m][i] (transposed at store)
    __shared__ float Bs[32][68];   // [m][n] (transposed at store)
    const int n0 = blockIdx.x * 64;
    const int i0 = blockIdx.y * 64;
    const int b  = blockIdx.z;
    const int tid = threadIdx.x;
    const int tx = tid & 15, ty = tid >> 4;
    const float* Ab = A + (size_t)b * LL * DM;
    const float* Gb = gate + (size_t)b * NH * DM;

    float acc[4][4] = {{0.f,0.f,0.f,0.f},{0.f,0.f,0.f,0.f},
                       {0.f,0.f,0.f,0.f},{0.f,0.f,0.f,0.f}};

    for (int m0 = 0; m0 < DM; m0 += 32) {
        #pragma unroll
        for (int p = 0; p < 2; ++p) {
            int f   = tid + p * 256;      // 512 float4 per operand tile
            int row = f >> 3;             // 0..63
            int m4  = (f & 7) << 2;       // 0..28
            float4 v = *(const float4*)(Ab + (size_t)(i0 + row) * DM + m0 + m4);
            As[m4 + 0][row] = v.x; As[m4 + 1][row] = v.y;
            As[m4 + 2][row] = v.z; As[m4 + 3][row] = v.w;
            size_t off = (size_t)(n0 + row) * DM + m0 + m4;
            float4 w = *(const float4*)(W + off);
            float4 g = *(const float4*)(Gb + off);
            Bs[m4 + 0][row] = w.x * g.x; Bs[m4 + 1][row] = w.y * g.y;
            Bs[m4 + 2][row] = w.z * g.z; Bs[m4 + 3][row] = w.w * g.w;
        }
        __syncthreads();
        #pragma unroll
        for (int k = 0; k < 32; ++k) {
            float4 a4 = *(const float4*)&As[k][ty << 2];
            float4 b4 = *(const float4*)&Bs[k][tx << 2];
            float av[4] = {a4.x, a4.y, a4.z, a4.w};
            float bv[4] = {b4.x, b4.y, b4.z, b4.w};
            #pragma unroll
            for (int i = 0; i < 4; ++i)
                #pragma unroll
                for (int j = 0; j < 4; ++j)
                    acc[i][j] = fmaf(av[i], bv[j], acc[i][j]);
        }
        __syncthreads();
    }
    #pragma unroll
    for (int i = 0; i < 4; ++i) {
        int gi = i0 + (ty << 2) + i;
        float4 o;
        o.x = acc[i][0] + bias[n0 + (tx << 2) + 0];
        o.y = acc[i][1] + bias[n0 + (tx << 2) + 1];
        o.z = acc[i][2] + bias[n0 + (tx << 2) + 2];
        o.w = acc[i][3] + bias[n0 + (tx << 2) + 3];
        *(float4*)(C + ((size_t)b * LL + gi) * NH + n0 + (tx << 2)) = o;
    }
}

// ---------------------------------------------------------------------------
// Output projection: C[i][d] = sum_n A[i][n] * W[d][n] + bias[d]
// A is [B*L=4096][1024]. Same tiling as proj_kernel, no gate, no batch dim.
// ---------------------------------------------------------------------------
__global__ __launch_bounds__(256) void out_kernel(
    const float* __restrict__ A, const float* __restrict__ W,
    const float* __restrict__ bias, float* __restrict__ C)
{
    __shared__ float As[32][68];
    __shared__ float Bs[32][68];
    const int n0 = blockIdx.x * 64;   // d tile
    const int i0 = blockIdx.y * 64;   // row tile over B*L
    const int tid = threadIdx.x;
    const int tx = tid & 15, ty = tid >> 4;

    float acc[4][4] = {{0.f,0.f,0.f,0.f},{0.f,0.f,0.f,0.f},
                       {0.f,0.f,0.f,0.f},{0.f,0.f,0.f,0.f}};

    for (int m0 = 0; m0 < NH; m0 += 32) {
        #pragma unroll
        for (int p = 0; p < 2; ++p) {
            int f   = tid + p * 256;
            int row = f >> 3;
            int m4  = (f & 7) << 2;
            float4 v = *(const float4*)(A + (size_t)(i0 + row) * NH + m0 + m4);
            As[m4 + 0][row] = v.x; As[m4 + 1][row] = v.y;
            As[m4 + 2][row] = v.z; As[m4 + 3][row] = v.w;
            float4 w = *(const float4*)(W + (size_t)(n0 + row) * NH + m0 + m4);
            Bs[m4 + 0][row] = w.x; Bs[m4 + 1][row] = w.y;
            Bs[m4 + 2][row] = w.z; Bs[m4 + 3][row] = w.w;
        }
        __syncthreads();
        #pragma unroll
        for (int k = 0; k < 32; ++k) {
            float4 a4 = *(const float4*)&As[k][ty << 2];
            float4 b4 = *(const float4*)&Bs[k][tx << 2];
            float av[4] = {a4.x, a4.y, a4.z, a4.w};
            float bv[4] = {b4.x, b4.y, b4.z, b4.w};
            #pragma unroll
            for (int i = 0; i < 4; ++i)
                #pragma unroll
                for (int j = 0; j < 4; ++j)
                    acc[i][j] = fmaf(av[i], bv[j], acc[i][j]);
        }
        __syncthreads();
    }
    #pragma unroll
    for (int i = 0; i < 4; ++i) {
        int gi = i0 + (ty << 2) + i;
        float4 o;
        o.x = acc[i][0] + bias[n0 + (tx << 2) + 0];
        o.y = acc[i][1] + bias[n0 + (tx << 2) + 1];
        o.z = acc[i][2] + bias[n0 + (tx << 2) + 2];
        o.w = acc[i][3] + bias[n0 + (tx << 2) + 3];
        *(float4*)(C + (size_t)gi * DM + n0 + (tx << 2)) = o;
    }
}

// ---------------------------------------------------------------------------
// Transpose K[b][s][n] -> Kt[b][n][s]  (64x64 tiles via LDS, pad 65 => 2-way max)
// ---------------------------------------------------------------------------
__global__ __launch_bounds__(256) void transpose_kernel(
    const float* __restrict__ Kin, float* __restrict__ Kt)
{
    __shared__ float T[64][65];
    const int s0 = blockIdx.x * 64;
    const int n0 = blockIdx.y * 64;
    const int b  = blockIdx.z;
    const int tid = threadIdx.x;
    const float* Kb = Kin + (size_t)b * SS * NH;
    float* Ktb = Kt + (size_t)b * NH * SS;
    #pragma unroll
    for (int p = 0; p < 4; ++p) {
        int f = tid + p * 256;
        int row = f >> 4;           // s local
        int n4  = (f & 15) << 2;
        float4 v = *(const float4*)(Kb + (size_t)(s0 + row) * NH + n0 + n4);
        T[row][n4 + 0] = v.x; T[row][n4 + 1] = v.y;
        T[row][n4 + 2] = v.z; T[row][n4 + 3] = v.w;
    }
    __syncthreads();
    #pragma unroll
    for (int p = 0; p < 4; ++p) {
        int f = tid + p * 256;
        int nrow = f >> 4;          // n local
        int s4   = (f & 15) << 2;
        float4 o = make_float4(T[s4 + 0][nrow], T[s4 + 1][nrow],
                               T[s4 + 2][nrow], T[s4 + 3][nrow]);
        *(float4*)(Ktb + (size_t)(n0 + nrow) * SS + s0 + s4) = o;
    }
}

// ---------------------------------------------------------------------------
// Fused scores + softmax. One block = 16 query rows of one (b,h).
// Scores kept in registers (64 f32/thread), softmax via 16-lane shuffles,
// attn written exactly once (coalesced float4).
// Thread (r=tid/16, tx=tid%15) owns s = t*64 + tx*4 + {0..3}, t=0..15.
// ---------------------------------------------------------------------------
__global__ __launch_bounds__(256) void attn_kernel(
    const float* __restrict__ Q, const float* __restrict__ Kt,
    float* __restrict__ attn)
{
    __shared__ float Qs[16][68];
    __shared__ float Ks[64][68];   // [k][s] tile
    const int r0 = blockIdx.x * 16;
    const int h  = blockIdx.y;
    const int b  = blockIdx.z;
    const int tid = threadIdx.x;
    const int tx = tid & 15, r = tid >> 4;

    {   // Q tile: 16 rows x 64 k = 256 float4, one per thread
        int row = tid >> 4;
        int k4  = (tid & 15) << 2;
        float4 v = *(const float4*)(Q + ((size_t)b * LL + r0 + row) * NH + h * DKH + k4);
        *(float4*)&Qs[row][k4] = v;
    }
    const float* Ktb = Kt + ((size_t)b * NH + h * DKH) * SS;

    float4 acc[16];
    #pragma unroll
    for (int t = 0; t < 16; ++t) acc[t] = make_float4(0.f, 0.f, 0.f, 0.f);

    #pragma unroll
    for (int t = 0; t < 16; ++t) {
        __syncthreads();
        #pragma unroll
        for (int p = 0; p < 4; ++p) {
            int f = tid + p * 256;
            int krow = f >> 4;           // 0..63
            int s4   = (f & 15) << 2;
            float4 v = *(const float4*)(Ktb + (size_t)krow * SS + t * 64 + s4);
            *(float4*)&Ks[krow][s4] = v;
        }
        __syncthreads();
        #pragma unroll 8
        for (int k = 0; k < 64; ++k) {
            float qv  = Qs[r][k];
            float4 kv = *(const float4*)&Ks[k][tx << 2];
            acc[t].x = fmaf(qv, kv.x, acc[t].x);
            acc[t].y = fmaf(qv, kv.y, acc[t].y);
            acc[t].z = fmaf(qv, kv.z, acc[t].z);
            acc[t].w = fmaf(qv, kv.w, acc[t].w);
        }
    }

    // ---- softmax over the full row (scale folded into exp) ----
    float mx = -1e30f;
    #pragma unroll
    for (int t = 0; t < 16; ++t)
        mx = fmaxf(mx, fmaxf(fmaxf(acc[t].x, acc[t].y), fmaxf(acc[t].z, acc[t].w)));
    #pragma unroll
    for (int off = 8; off; off >>= 1) mx = fmaxf(mx, __shfl_xor(mx, off, 16));

    float sum = 0.f;
    #pragma unroll
    for (int t = 0; t < 16; ++t) {
        acc[t].x = __expf(SM_SCALE * (acc[t].x - mx));
        acc[t].y = __expf(SM_SCALE * (acc[t].y - mx));
        acc[t].z = __expf(SM_SCALE * (acc[t].z - mx));
        acc[t].w = __expf(SM_SCALE * (acc[t].w - mx));
        sum += acc[t].x + acc[t].y + acc[t].z + acc[t].w;
    }
    #pragma unroll
    for (int off = 8; off; off >>= 1) sum += __shfl_xor(sum, off, 16);
    float inv = 1.f / sum;

    float* arow = attn + (((size_t)b * HH + h) * LL + r0 + r) * SS;
    #pragma unroll
    for (int t = 0; t < 16; ++t) {
        float4 o = make_float4(acc[t].x * inv, acc[t].y * inv,
                               acc[t].z * inv, acc[t].w * inv);
        *(float4*)(arow + t * 64 + (tx << 2)) = o;
    }
}

// ---------------------------------------------------------------------------
// PV: ctx[b][l][h*64+k] = sum_s attn[b][h][l][s] * V[b][s][h*64+k]
// BM=64(l) x BN=64(k, full head) x BK=32(s)
// ---------------------------------------------------------------------------
__global__ __launch_bounds__(256) void pv_kernel(
    const float* __restrict__ attn, const float* __restrict__ V,
    float* __restrict__ ctx)
{
    __shared__ float As[32][68];  // [s][l] transposed at store
    __shared__ float Bs[32][68];  // [s][k] natural
    const int l0 = blockIdx.x * 64;
    const int h  = blockIdx.y;
    const int b  = blockIdx.z;
    const int tid = threadIdx.x;
    const int tx = tid & 15, ty = tid >> 4;
    const float* Ab = attn + ((size_t)b * HH + h) * LL * SS;
    const float* Vb = V + (size_t)b * SS * NH + h * DKH;

    float acc[4][4] = {{0.f,0.f,0.f,0.f},{0.f,0.f,0.f,0.f},
                       {0.f,0.f,0.f,0.f},{0.f,0.f,0.f,0.f}};

    for (int s0 = 0; s0 < SS; s0 += 32) {
        #pragma unroll
        for (int p = 0; p < 2; ++p) {
            int f   = tid + p * 256;
            int row = f >> 3;            // l local 0..63
            int s4  = (f & 7) << 2;      // 0..28
            float4 v = *(const float4*)(Ab + (size_t)(l0 + row) * SS + s0 + s4);
            As[s4 + 0][row] = v.x; As[s4 + 1][row] = v.y;
            As[s4 + 2][row] = v.z; As[s4 + 3][row] = v.w;
            int srow = f >> 4;           // s local 0..31
            int k4   = (f & 15) << 2;
            float4 w = *(const float4*)(Vb + (size_t)(s0 + srow) * NH + k4);
            *(float4*)&Bs[srow][k4] = w;
        }
        __syncthreads();
        #pragma unroll
        for (int s = 0; s < 32; ++s) {
            float4 a4 = *(const float4*)&As[s][ty << 2];
            float4 b4 = *(const float4*)&Bs[s][tx << 2];
            float av[4] = {a4.x, a4.y, a4.z, a4.w};
            float bv[4] = {b4.x, b4.y, b4.z, b4.w};
            #pragma unroll
            for (int i = 0; i < 4; ++i)
                #pragma unroll
                for (int j = 0; j < 4; ++j)
                    acc[i][j] = fmaf(av[i], bv[j], acc[i][j]);
        }
        __syncthreads();
    }
    #pragma unroll
    for (int i = 0; i < 4; ++i) {
        float4 o = make_float4(acc[i][0], acc[i][1], acc[i][2], acc[i][3]);
        *(float4*)(ctx + ((size_t)b * LL + l0 + (ty << 2) + i) * NH + h * DKH + (tx << 2)) = o;
    }
}

// ---------------------------------------------------------------------------
extern "C" void kernel_launch(void* const* d_in, const int* in_sizes, int n_in,
                              void* d_out, int out_size, void* d_ws, size_t ws_size,
                              hipStream_t stream)
{
    const float* queries = (const float*)d_in[0];
    const float* keys    = (const float*)d_in[1];
    const float* values  = (const float*)d_in[2];
    const float* gate    = (const float*)d_in[3];
    const float* W_q     = (const float*)d_in[4];
    const float* b_q     = (const float*)d_in[5];
    const float* W_k     = (const float*)d_in[6];
    const float* b_k     = (const float*)d_in[7];
    const float* W_v     = (const float*)d_in[8];
    const float* b_v     = (const float*)d_in[9];
    const float* W_o     = (const float*)d_in[10];
    const float* b_o     = (const float*)d_in[11];

    float* out  = (float*)d_out;                       // [B,L,DM]
    float* attn = out + (size_t)BB * LL * DM;          // [B,H,L,S]

    // workspace: Q,K,V,Kt (4M floats each) = 64 MB; ctx aliases dead K buffer
    float* ws  = (float*)d_ws;
    float* Qw  = ws;
    float* Kw  = ws + (size_t)1 * 4194304;
    float* Vw  = ws + (size_t)2 * 4194304;
    float* Ktw = ws + (size_t)3 * 4194304;
    float* ctx = Kw;   // K is dead after transpose_kernel

    dim3 blk(256, 1, 1);
    proj_kernel<<<dim3(16, 16, BB), blk, 0, stream>>>(queries, W_q, gate, b_q, Qw);
    proj_kernel<<<dim3(16, 16, BB), blk, 0, stream>>>(keys,    W_k, gate, b_k, Kw);
    proj_kernel<<<dim3(16, 16, BB), blk, 0, stream>>>(values,  W_v, gate, b_v, Vw);
    transpose_kernel<<<dim3(16, 16, BB), blk, 0, stream>>>(Kw, Ktw);
    attn_kernel<<<dim3(LL / 16, HH, BB), blk, 0, stream>>>(Qw, Ktw, attn);
    pv_kernel<<<dim3(16, HH, BB), blk, 0, stream>>>(attn, Vw, ctx);
    out_kernel<<<dim3(16, 64, 1), blk, 0, stream>>>(ctx, W_o, b_o, out);
}

// Round 2
// 287.561 us; speedup vs baseline: 2.9331x; 2.9331x over previous
//
#include <hip/hip_runtime.h>
#include <math.h>

#define BB 4
#define LL 1024
#define SS 1024
#define DM 1024
#define HH 16
#define DKH 64
#define NH 1024
#define SM_SCALE 0.125f

typedef __attribute__((ext_vector_type(8))) short bf16x8;
typedef __attribute__((ext_vector_type(4))) float f32x4;
typedef unsigned short ushort_t;
typedef unsigned int uint_t;

#define MFMA16(a, b, c) __builtin_amdgcn_mfma_f32_16x16x32_bf16((a), (b), (c), 0, 0, 0)

__device__ __forceinline__ ushort_t f2b(float f) {
    union { float f; uint_t u; } x; x.f = f;
    uint_t r = x.u + 0x7fffu + ((x.u >> 16) & 1u);   // RNE to bf16
    return (ushort_t)(r >> 16);
}

__device__ __forceinline__ void gload_lds16(const void* g, void* l) {
    __builtin_amdgcn_global_load_lds(
        (const __attribute__((address_space(1))) unsigned int*)g,
        (__attribute__((address_space(3))) unsigned int*)l, 16, 0, 0);
}

// ---------------------------------------------------------------------------
// Prep: fp32 -> bf16 conversions + gated weights.
//   regions 0-2: Xq/Xk/Xv  = bf16(queries/keys/values)        [B*L*DM each]
//   regions 3-5: Gq/Gk/Gv  = bf16(gate[b] * W_x)              [B*NH*DM each]
//   region  6  : Wo2       = bf16(W_o)                        [DM*NH]
// ---------------------------------------------------------------------------
__global__ __launch_bounds__(256) void prep_kernel(
    const float* __restrict__ q, const float* __restrict__ k, const float* __restrict__ v,
    const float* __restrict__ gate,
    const float* __restrict__ Wq, const float* __restrict__ Wk, const float* __restrict__ Wv,
    const float* __restrict__ Wo,
    ushort_t* __restrict__ Xq, ushort_t* __restrict__ Xk, ushort_t* __restrict__ Xv,
    ushort_t* __restrict__ Gq, ushort_t* __restrict__ Gk, ushort_t* __restrict__ Gv,
    ushort_t* __restrict__ Wo2)
{
    const int NCHUNK = 6 * 524288 + 131072;
    for (int c = blockIdx.x * 256 + threadIdx.x; c < NCHUNK; c += gridDim.x * 256) {
        int r = c >> 19;
        const float* src; const float* g2 = nullptr; ushort_t* dst; int e;
        if (r < 3) {
            e = (c & 524287) * 8;
            src = (r == 0 ? q : r == 1 ? k : v) + e;
            dst = (r == 0 ? Xq : r == 1 ? Xk : Xv) + e;
        } else if (r < 6) {
            e = (c & 524287) * 8;
            int nm = e & 1048575;
            int b  = e >> 20;
            src = (r == 3 ? Wq : r == 4 ? Wk : Wv) + nm;
            g2  = gate + (size_t)b * 1048576 + nm;
            dst = (r == 3 ? Gq : r == 4 ? Gv == nullptr ? Gk : Gk : Gv) + e;  // r==4 -> Gk
        } else {
            e = (c - 6 * 524288) * 8;
            src = Wo + e; dst = Wo2 + e;
        }
        float4 a  = *(const float4*)(src);
        float4 b4 = *(const float4*)(src + 4);
        if (g2) {
            float4 ga = *(const float4*)(g2);
            float4 gb = *(const float4*)(g2 + 4);
            a.x *= ga.x; a.y *= ga.y; a.z *= ga.z; a.w *= ga.w;
            b4.x *= gb.x; b4.y *= gb.y; b4.z *= gb.z; b4.w *= gb.w;
        }
        uint4 o;
        o.x = f2b(a.x)  | ((uint_t)f2b(a.y)  << 16);
        o.y = f2b(a.z)  | ((uint_t)f2b(a.w)  << 16);
        o.z = f2b(b4.x) | ((uint_t)f2b(b4.y) << 16);
        o.w = f2b(b4.z) | ((uint_t)f2b(b4.w) << 16);
        *(uint4*)dst = o;
    }
}

// ---------------------------------------------------------------------------
// bf16 MFMA GEMM: C[b][m][n] = sum_k A[b][m][k]*B[b][n][k] + bias[n or m]
// 128x128 tile, BK=64, 256 thr (4 waves, 2x2), 4x4 16x16x32 frags per wave.
// LDS XOR-swizzled (T2), staged via global_load_lds width=16 with
// pre-swizzled global source (linear LDS dest).
// ---------------------------------------------------------------------------
template<bool BIAS_ROW, bool OUT_BF16>
__global__ __launch_bounds__(256) void gemm_bf16(
    const ushort_t* __restrict__ A, const ushort_t* __restrict__ B,
    const float* __restrict__ bias, void* __restrict__ Cout,
    int M, int N, int K, int sA, int sB, int sC)
{
    __shared__ ushort_t As[128 * 64];
    __shared__ ushort_t Bs[128 * 64];
    const int bn = blockIdx.x * 128;
    const int bm = blockIdx.y * 128;
    const int b  = blockIdx.z;
    const int tid  = threadIdx.x;
    const int lane = tid & 63;
    const int w    = tid >> 6;
    const int wr = w >> 1, wc = w & 1;
    const int lr = lane & 15, lk = lane >> 4;

    const ushort_t* Ab = A + (size_t)b * sA;
    const ushort_t* Bb = B + (size_t)b * sB;

    f32x4 acc[4][4];
    #pragma unroll
    for (int i = 0; i < 4; ++i)
        #pragma unroll
        for (int j = 0; j < 4; ++j)
            acc[i][j] = (f32x4){0.f, 0.f, 0.f, 0.f};

    for (int k0 = 0; k0 < K; k0 += 64) {
        #pragma unroll
        for (int p = 0; p < 4; ++p) {
            int f = p * 256 + tid;
            int row = f >> 3, seg = f & 7;
            int kb = (seg * 8) ^ ((row & 7) * 8);     // pre-swizzled source chunk
            gload_lds16(Ab + (size_t)(bm + row) * K + k0 + kb,
                        (char*)As + ((p * 256 + (w << 6)) << 4));
            gload_lds16(Bb + (size_t)(bn + row) * K + k0 + kb,
                        (char*)Bs + ((p * 256 + (w << 6)) << 4));
        }
        __syncthreads();
        #pragma unroll
        for (int kk = 0; kk < 2; ++kk) {
            bf16x8 af[4], bfr[4];
            #pragma unroll
            for (int i = 0; i < 4; ++i) {
                int row = wr * 64 + i * 16 + lr;
                af[i] = *(const bf16x8*)&As[row * 64 + ((lk * 8 + kk * 32) ^ ((row & 7) * 8))];
            }
            #pragma unroll
            for (int j = 0; j < 4; ++j) {
                int row = wc * 64 + j * 16 + lr;
                bfr[j] = *(const bf16x8*)&Bs[row * 64 + ((lk * 8 + kk * 32) ^ ((row & 7) * 8))];
            }
            #pragma unroll
            for (int i = 0; i < 4; ++i)
                #pragma unroll
                for (int j = 0; j < 4; ++j)
                    acc[i][j] = MFMA16(af[i], bfr[j], acc[i][j]);
        }
        __syncthreads();
    }

    #pragma unroll
    for (int i = 0; i < 4; ++i) {
        #pragma unroll
        for (int j = 0; j < 4; ++j) {
            #pragma unroll
            for (int r = 0; r < 4; ++r) {
                int row = bm + wr * 64 + i * 16 + lk * 4 + r;
                int col = bn + wc * 64 + j * 16 + lr;
                float vv = acc[i][j][r] + bias[BIAS_ROW ? row : col];
                if (OUT_BF16)
                    ((ushort_t*)Cout)[(size_t)b * sC + (size_t)row * N + col] = f2b(vv);
                else
                    ((float*)Cout)[(size_t)b * sC + (size_t)row * N + col] = vv;
            }
        }
    }
}

// ---------------------------------------------------------------------------
// Fused QK^T + softmax -> attn (fp32). Block = 64 q-rows of one (b,h),
// 4 waves x 16 rows. Q-frags in regs; K tiles streamed via LDS.
// Pass 1: accumulate per-row exp-sums (no max-sub: |score| bounded, fp32 safe).
// Pass 2: recompute scores (bitwise-identical MFMA), normalize, store.
// ---------------------------------------------------------------------------
__global__ __launch_bounds__(256) void attn_kernel(
    const ushort_t* __restrict__ Q, const ushort_t* __restrict__ Kmat,
    float* __restrict__ attn)
{
    __shared__ ushort_t Ks[64 * 64];
    const int r0 = blockIdx.x * 64;
    const int h  = blockIdx.y;
    const int b  = blockIdx.z;
    const int tid  = threadIdx.x;
    const int lane = tid & 63;
    const int w    = tid >> 6;
    const int lr = lane & 15, lk = lane >> 4;

    bf16x8 aq[2];
    {
        const ushort_t* Qrow = Q + ((size_t)b * LL + r0 + w * 16 + lr) * NH + h * DKH;
        aq[0] = *(const bf16x8*)(Qrow + lk * 8);
        aq[1] = *(const bf16x8*)(Qrow + lk * 8 + 32);
    }
    const ushort_t* Kp = Kmat + (size_t)b * SS * NH + h * DKH;

    float lsum[4] = {0.f, 0.f, 0.f, 0.f};

    for (int pass = 0; pass < 2; ++pass) {
        float* Ob = attn + (((size_t)b * HH + h) * LL + r0 + w * 16) * SS;
        for (int t = 0; t < 16; ++t) {
            #pragma unroll
            for (int p = 0; p < 2; ++p) {
                int f = p * 256 + tid;
                int row = f >> 3, seg = f & 7;
                int kb = (seg * 8) ^ ((row & 7) * 8);
                gload_lds16(Kp + (size_t)(t * 64 + row) * NH + kb,
                            (char*)Ks + ((p * 256 + (w << 6)) << 4));
            }
            __syncthreads();
            f32x4 acc[4];
            #pragma unroll
            for (int j = 0; j < 4; ++j) acc[j] = (f32x4){0.f, 0.f, 0.f, 0.f};
            #pragma unroll
            for (int kk = 0; kk < 2; ++kk) {
                #pragma unroll
                for (int j = 0; j < 4; ++j) {
                    int row = j * 16 + lr;
                    bf16x8 bk = *(const bf16x8*)&Ks[row * 64 + ((lk * 8 + kk * 32) ^ ((row & 7) * 8))];
                    acc[j] = MFMA16(aq[kk], bk, acc[j]);
                }
            }
            if (pass == 0) {
                #pragma unroll
                for (int r = 0; r < 4; ++r)
                    lsum[r] += __expf(SM_SCALE * acc[0][r]) + __expf(SM_SCALE * acc[1][r])
                             + __expf(SM_SCALE * acc[2][r]) + __expf(SM_SCALE * acc[3][r]);
            } else {
                #pragma unroll
                for (int j = 0; j < 4; ++j)
                    #pragma unroll
                    for (int r = 0; r < 4; ++r)
                        Ob[(size_t)(lk * 4 + r) * SS + t * 64 + j * 16 + lr] =
                            __expf(SM_SCALE * acc[j][r]) * lsum[r];
            }
            __syncthreads();
        }
        if (pass == 0) {
            #pragma unroll
            for (int r = 0; r < 4; ++r) {
                float s = lsum[r];
                s += __shfl_xor(s, 1);
                s += __shfl_xor(s, 2);
                s += __shfl_xor(s, 4);
                s += __shfl_xor(s, 8);
                lsum[r] = 1.0f / s;      // reuse as inv-denominator in pass 2
            }
        }
    }
}

// ---------------------------------------------------------------------------
// PV: ctx[b][l][h*64+dk] = sum_s attn[b][h][l][s] * Vt[b][h*64+dk][s]
// BM=128(l) x BN=64(dk) x BK=64(s). A reg-staged (fp32->bf16 + swizzled
// ds_write); B via global_load_lds. Output bf16 ctx.
// ---------------------------------------------------------------------------
__global__ __launch_bounds__(256) void pv_kernel(
    const float* __restrict__ P, const ushort_t* __restrict__ Vt,
    ushort_t* __restrict__ ctx)
{
    __shared__ ushort_t Ps[128 * 64];
    __shared__ ushort_t Vs[64 * 64];
    const int l0 = blockIdx.x * 128;
    const int h  = blockIdx.y;
    const int b  = blockIdx.z;
    const int tid  = threadIdx.x;
    const int lane = tid & 63;
    const int w    = tid >> 6;
    const int lr = lane & 15, lk = lane >> 4;

    const float*    Pb = P  + ((size_t)b * HH + h) * LL * SS;
    const ushort_t* Vb = Vt + ((size_t)b * NH + h * DKH) * SS;

    f32x4 acc[2][4];
    #pragma unroll
    for (int i = 0; i < 2; ++i)
        #pragma unroll
        for (int j = 0; j < 4; ++j)
            acc[i][j] = (f32x4){0.f, 0.f, 0.f, 0.f};

    for (int s0 = 0; s0 < SS; s0 += 64) {
        #pragma unroll
        for (int p = 0; p < 4; ++p) {
            int f = p * 256 + tid;
            int row = f >> 3, seg = f & 7;
            const float* src = Pb + (size_t)(l0 + row) * SS + s0 + seg * 8;
            float4 x = *(const float4*)src;
            float4 y = *(const float4*)(src + 4);
            uint4 o;
            o.x = f2b(x.x) | ((uint_t)f2b(x.y) << 16);
            o.y = f2b(x.z) | ((uint_t)f2b(x.w) << 16);
            o.z = f2b(y.x) | ((uint_t)f2b(y.y) << 16);
            o.w = f2b(y.z) | ((uint_t)f2b(y.w) << 16);
            *(uint4*)&Ps[row * 64 + ((seg * 8) ^ ((row & 7) * 8))] = o;
        }
        #pragma unroll
        for (int p = 0; p < 2; ++p) {
            int f = p * 256 + tid;
            int row = f >> 3, seg = f & 7;
            int kb = (seg * 8) ^ ((row & 7) * 8);
            gload_lds16(Vb + (size_t)row * SS + s0 + kb,
                        (char*)Vs + ((p * 256 + (w << 6)) << 4));
        }
        __syncthreads();
        #pragma unroll
        for (int kk = 0; kk < 2; ++kk) {
            bf16x8 af[2], bfr[4];
            #pragma unroll
            for (int i = 0; i < 2; ++i) {
                int row = w * 32 + i * 16 + lr;
                af[i] = *(const bf16x8*)&Ps[row * 64 + ((lk * 8 + kk * 32) ^ ((row & 7) * 8))];
            }
            #pragma unroll
            for (int j = 0; j < 4; ++j) {
                int row = j * 16 + lr;
                bfr[j] = *(const bf16x8*)&Vs[row * 64 + ((lk * 8 + kk * 32) ^ ((row & 7) * 8))];
            }
            #pragma unroll
            for (int i = 0; i < 2; ++i)
                #pragma unroll
                for (int j = 0; j < 4; ++j)
                    acc[i][j] = MFMA16(af[i], bfr[j], acc[i][j]);
        }
        __syncthreads();
    }

    #pragma unroll
    for (int i = 0; i < 2; ++i)
        #pragma unroll
        for (int j = 0; j < 4; ++j)
            #pragma unroll
            for (int r = 0; r < 4; ++r) {
                int row = l0 + w * 32 + i * 16 + lk * 4 + r;
                int col = h * DKH + j * 16 + lr;
                ctx[((size_t)b * LL + row) * NH + col] = f2b(acc[i][j][r]);
            }
}

// ---------------------------------------------------------------------------
extern "C" void kernel_launch(void* const* d_in, const int* in_sizes, int n_in,
                              void* d_out, int out_size, void* d_ws, size_t ws_size,
                              hipStream_t stream)
{
    const float* queries = (const float*)d_in[0];
    const float* keys    = (const float*)d_in[1];
    const float* values  = (const float*)d_in[2];
    const float* gate    = (const float*)d_in[3];
    const float* W_q     = (const float*)d_in[4];
    const float* b_q     = (const float*)d_in[5];
    const float* W_k     = (const float*)d_in[6];
    const float* b_k     = (const float*)d_in[7];
    const float* W_v     = (const float*)d_in[8];
    const float* b_v     = (const float*)d_in[9];
    const float* W_o     = (const float*)d_in[10];
    const float* b_o     = (const float*)d_in[11];

    float* out  = (float*)d_out;                        // [B,L,DM]
    float* attn = out + (size_t)BB * LL * DM;           // [B,H,L,S]

    char* ws = (char*)d_ws;
    const size_t U = (size_t)8 << 20;                   // 8 MiB slot (4.19M bf16)
    ushort_t* Xq  = (ushort_t*)(ws);
    ushort_t* Xk  = (ushort_t*)(ws + 1 * U);
    ushort_t* Xv  = (ushort_t*)(ws + 2 * U);
    ushort_t* Gq  = (ushort_t*)(ws + 3 * U);
    ushort_t* Gk  = (ushort_t*)(ws + 4 * U);
    ushort_t* Gv  = (ushort_t*)(ws + 5 * U);
    ushort_t* Vt  = (ushort_t*)(ws + 6 * U);
    ushort_t* Wo2 = (ushort_t*)(ws + 7 * U);            // 2 MiB
    ushort_t* Qb  = Xv;   // Xv dead after Vt-GEMM
    ushort_t* Kb  = Gv;   // Gv dead after Vt-GEMM
    ushort_t* ctx = Xq;   // Xq dead after Q-GEMM

    const int S1M = 1048576;
    dim3 blk(256, 1, 1);

    prep_kernel<<<2048, blk, 0, stream>>>(queries, keys, values, gate,
                                          W_q, W_k, W_v, W_o,
                                          Xq, Xk, Xv, Gq, Gk, Gv, Wo2);
    // Vt[b][n][s] = sum_m Gv[b][n][m] * Xv[b][s][m] + b_v[n]   (bias per row)
    gemm_bf16<true,  true ><<<dim3(8, 8, BB), blk, 0, stream>>>(Gv, Xv, b_v, Vt,
                                                                1024, 1024, 1024, S1M, S1M, S1M);
    // Q[b][l][n] = sum_m Xq[b][l][m] * Gq[b][n][m] + b_q[n]
    gemm_bf16<false, true ><<<dim3(8, 8, BB), blk, 0, stream>>>(Xq, Gq, b_q, Qb,
                                                                1024, 1024, 1024, S1M, S1M, S1M);
    gemm_bf16<false, true ><<<dim3(8, 8, BB), blk, 0, stream>>>(Xk, Gk, b_k, Kb,
                                                                1024, 1024, 1024, S1M, S1M, S1M);
    attn_kernel<<<dim3(16, HH, BB), blk, 0, stream>>>(Qb, Kb, attn);
    pv_kernel<<<dim3(8, HH, BB), blk, 0, stream>>>(attn, Vt, ctx);
    // out[i][d] = sum_n ctx[i][n] * Wo2[d][n] + b_o[d]
    gemm_bf16<false, false><<<dim3(8, 32, 1), blk, 0, stream>>>(ctx, Wo2, b_o, out,
                                                                4096, 1024, 1024, 0, 0, 0);
}

// Round 3
// 196.260 us; speedup vs baseline: 4.2976x; 1.4652x over previous
//
#include <hip/hip_runtime.h>
#include <math.h>

#define BB 4
#define LL 1024
#define SS 1024
#define DM 1024
#define HH 16
#define DKH 64
#define NH 1024
#define SM_SCALE 0.125f

typedef __attribute__((ext_vector_type(8))) short bf16x8;
typedef __attribute__((ext_vector_type(4))) float f32x4;
typedef unsigned short ushort_t;
typedef unsigned int uint_t;

#define MFMA16(a, b, c) __builtin_amdgcn_mfma_f32_16x16x32_bf16((a), (b), (c), 0, 0, 0)

__device__ __forceinline__ ushort_t f2b(float f) {
    union { float f; uint_t u; } x; x.f = f;
    uint_t r = x.u + 0x7fffu + ((x.u >> 16) & 1u);   // RNE to bf16
    return (ushort_t)(r >> 16);
}

__device__ __forceinline__ void gload_lds16(const void* g, void* l) {
    __builtin_amdgcn_global_load_lds(
        (const __attribute__((address_space(1))) unsigned int*)g,
        (__attribute__((address_space(3))) unsigned int*)l, 16, 0, 0);
}

// ---------------------------------------------------------------------------
// Prep: fp32 -> bf16; gate read ONCE serving all three gated weights.
// ---------------------------------------------------------------------------
__device__ __forceinline__ void cvt8(const float* src, ushort_t* dst, const float* g2) {
    float4 a  = *(const float4*)(src);
    float4 b4 = *(const float4*)(src + 4);
    if (g2) {
        float4 ga = *(const float4*)(g2);
        float4 gb = *(const float4*)(g2 + 4);
        a.x *= ga.x; a.y *= ga.y; a.z *= ga.z; a.w *= ga.w;
        b4.x *= gb.x; b4.y *= gb.y; b4.z *= gb.z; b4.w *= gb.w;
    }
    uint4 o;
    o.x = f2b(a.x)  | ((uint_t)f2b(a.y)  << 16);
    o.y = f2b(a.z)  | ((uint_t)f2b(a.w)  << 16);
    o.z = f2b(b4.x) | ((uint_t)f2b(b4.y) << 16);
    o.w = f2b(b4.z) | ((uint_t)f2b(b4.w) << 16);
    *(uint4*)dst = o;
}

__global__ __launch_bounds__(256) void prep_kernel(
    const float* __restrict__ q, const float* __restrict__ k, const float* __restrict__ v,
    const float* __restrict__ gate,
    const float* __restrict__ Wq, const float* __restrict__ Wk, const float* __restrict__ Wv,
    const float* __restrict__ Wo,
    ushort_t* __restrict__ Xq, ushort_t* __restrict__ Xk, ushort_t* __restrict__ Xv,
    ushort_t* __restrict__ Gq, ushort_t* __restrict__ Gk, ushort_t* __restrict__ Gv,
    ushort_t* __restrict__ Wo2)
{
    const int XCH = 3 * 524288;
    const int GCH = 524288;
    const int WCH = 131072;
    for (int c = blockIdx.x * 256 + threadIdx.x; c < XCH + GCH + WCH; c += gridDim.x * 256) {
        if (c < XCH) {
            int r = c >> 19;
            int e = (c & 524287) * 8;
            cvt8((r == 0 ? q : r == 1 ? k : v) + e,
                 (r == 0 ? Xq : r == 1 ? Xk : Xv) + e, nullptr);
        } else if (c < XCH + GCH) {
            int e = (c - XCH) * 8;          // e = b*1048576 + nm
            int nm = e & 1048575;
            const float* g2 = gate + e;
            cvt8(Wq + nm, Gq + e, g2);
            cvt8(Wk + nm, Gk + e, g2);
            cvt8(Wv + nm, Gv + e, g2);
        } else {
            int e = (c - XCH - GCH) * 8;
            cvt8(Wo + e, Wo2 + e, nullptr);
        }
    }
}

// ---------------------------------------------------------------------------
// Merged Q/K/Vt GEMM. 128x128 tile, BK=64, 4 waves.
//   g=0: Qb[b][l][n] = Xq[l]·Gq[n] + bq[n]       (bias col)
//   g=1: Kb[b][s][n] = Xk[s]·Gk[n] + bk[n]       (bias col)
//   g=2: Vt[b][n][s] = Gv[n]·Xv[s] + bv[n]       (bias row)
// mode 0: z=b*3+g (12 blocks z); mode 1: z=b*2+g, g in {0,1}; mode 2: z=b, g=2.
// ---------------------------------------------------------------------------
__global__ __launch_bounds__(256) void qkv_gemm(
    const ushort_t* __restrict__ Xq, const ushort_t* __restrict__ Gq, const float* __restrict__ bq,
    const ushort_t* __restrict__ Xk, const ushort_t* __restrict__ Gk, const float* __restrict__ bk,
    const ushort_t* __restrict__ Xv, const ushort_t* __restrict__ Gv, const float* __restrict__ bv,
    ushort_t* __restrict__ Qb, ushort_t* __restrict__ Kb, ushort_t* __restrict__ Vt,
    int mode)
{
    __shared__ ushort_t As[128 * 64];
    __shared__ ushort_t Bs[128 * 64];
    const int z = blockIdx.z;
    int b, g;
    if (mode == 0)      { b = z / 3;  g = z % 3; }
    else if (mode == 1) { b = z >> 1; g = z & 1; }
    else                { b = z;      g = 2;     }
    const size_t off = (size_t)b * 1048576;
    const ushort_t *A, *B; const float* bias; ushort_t* C; bool brow;
    if (g == 0)      { A = Xq + off; B = Gq + off; bias = bq; C = Qb + off; brow = false; }
    else if (g == 1) { A = Xk + off; B = Gk + off; bias = bk; C = Kb + off; brow = false; }
    else             { A = Gv + off; B = Xv + off; bias = bv; C = Vt + off; brow = true;  }

    const int bn = blockIdx.x * 128;
    const int bm = blockIdx.y * 128;
    const int tid = threadIdx.x;
    const int lane = tid & 63;
    const int w = tid >> 6;
    const int wr = w >> 1, wc = w & 1;
    const int lr = lane & 15, lk = lane >> 4;

    f32x4 acc[4][4];
    #pragma unroll
    for (int i = 0; i < 4; ++i)
        #pragma unroll
        for (int j = 0; j < 4; ++j)
            acc[i][j] = (f32x4){0.f, 0.f, 0.f, 0.f};

    for (int k0 = 0; k0 < 1024; k0 += 64) {
        #pragma unroll
        for (int p = 0; p < 4; ++p) {
            int f = p * 256 + tid;
            int row = f >> 3, seg = f & 7;
            int kb2 = (seg * 8) ^ ((row & 7) * 8);
            gload_lds16(A + (size_t)(bm + row) * 1024 + k0 + kb2,
                        (char*)As + ((p * 256 + (w << 6)) << 4));
            gload_lds16(B + (size_t)(bn + row) * 1024 + k0 + kb2,
                        (char*)Bs + ((p * 256 + (w << 6)) << 4));
        }
        __syncthreads();
        #pragma unroll
        for (int kk = 0; kk < 2; ++kk) {
            bf16x8 af[4], bfr[4];
            #pragma unroll
            for (int i = 0; i < 4; ++i) {
                int row = wr * 64 + i * 16 + lr;
                af[i] = *(const bf16x8*)&As[row * 64 + ((lk * 8 + kk * 32) ^ ((row & 7) * 8))];
            }
            #pragma unroll
            for (int j = 0; j < 4; ++j) {
                int row = wc * 64 + j * 16 + lr;
                bfr[j] = *(const bf16x8*)&Bs[row * 64 + ((lk * 8 + kk * 32) ^ ((row & 7) * 8))];
            }
            #pragma unroll
            for (int i = 0; i < 4; ++i)
                #pragma unroll
                for (int j = 0; j < 4; ++j)
                    acc[i][j] = MFMA16(af[i], bfr[j], acc[i][j]);
        }
        __syncthreads();
    }

    #pragma unroll
    for (int i = 0; i < 4; ++i)
        #pragma unroll
        for (int j = 0; j < 4; ++j)
            #pragma unroll
            for (int r = 0; r < 4; ++r) {
                int row = bm + wr * 64 + i * 16 + lk * 4 + r;
                int col = bn + wc * 64 + j * 16 + lr;
                float vv = acc[i][j][r] + bias[brow ? row : col];
                C[(size_t)row * 1024 + col] = f2b(vv);
            }
}

// ---------------------------------------------------------------------------
// Fused QK^T + softmax + attn-write + PV. Block = 64 q-rows of one (b,h),
// 4 waves x 16 rows. Pass 1: exp-sum only. Pass 2: recompute scores,
// write normalized attn (f32), bf16 P tile -> per-wave LDS -> PV MFMA.
// ---------------------------------------------------------------------------
__global__ __launch_bounds__(256) void fused_attn_kernel(
    const ushort_t* __restrict__ Q, const ushort_t* __restrict__ Kmat,
    const ushort_t* __restrict__ Vt, float* __restrict__ attn,
    ushort_t* __restrict__ ctx)
{
    __shared__ ushort_t Ks[64 * 64];
    __shared__ ushort_t Vs[64 * 64];
    __shared__ ushort_t Ps[64 * 64];
    const int r0 = blockIdx.x * 64;
    const int h  = blockIdx.y;
    const int b  = blockIdx.z;
    const int tid = threadIdx.x, lane = tid & 63, w = tid >> 6;
    const int lr = lane & 15, lk = lane >> 4;

    bf16x8 aq[2];
    {
        const ushort_t* Qrow = Q + ((size_t)b * LL + r0 + w * 16 + lr) * NH + h * DKH;
        aq[0] = *(const bf16x8*)(Qrow + lk * 8);
        aq[1] = *(const bf16x8*)(Qrow + lk * 8 + 32);
    }
    const ushort_t* Kp = Kmat + (size_t)b * SS * NH + h * DKH;       // [s][dk], stride NH
    const ushort_t* Vp = Vt + ((size_t)b * NH + h * DKH) * SS;       // [dk][s], stride SS
    ushort_t* Psw = Ps + w * 1024;

    float inv[4] = {0.f, 0.f, 0.f, 0.f};

    // ---- pass 1: exp-sums ----
    for (int t = 0; t < 16; ++t) {
        __syncthreads();
        #pragma unroll
        for (int p = 0; p < 2; ++p) {
            int f = p * 256 + tid;
            int row = f >> 3, seg = f & 7;
            int kb2 = (seg * 8) ^ ((row & 7) * 8);
            gload_lds16(Kp + (size_t)(t * 64 + row) * NH + kb2,
                        (char*)Ks + ((p * 256 + (w << 6)) << 4));
        }
        __syncthreads();
        f32x4 acc[4];
        #pragma unroll
        for (int j = 0; j < 4; ++j) acc[j] = (f32x4){0.f, 0.f, 0.f, 0.f};
        #pragma unroll
        for (int kk = 0; kk < 2; ++kk)
            #pragma unroll
            for (int j = 0; j < 4; ++j) {
                int row = j * 16 + lr;
                bf16x8 bk2 = *(const bf16x8*)&Ks[row * 64 + ((lk * 8 + kk * 32) ^ ((row & 7) * 8))];
                acc[j] = MFMA16(aq[kk], bk2, acc[j]);
            }
        #pragma unroll
        for (int r = 0; r < 4; ++r)
            inv[r] += __expf(SM_SCALE * acc[0][r]) + __expf(SM_SCALE * acc[1][r])
                    + __expf(SM_SCALE * acc[2][r]) + __expf(SM_SCALE * acc[3][r]);
    }
    #pragma unroll
    for (int r = 0; r < 4; ++r) {
        float s = inv[r];
        s += __shfl_xor(s, 1);
        s += __shfl_xor(s, 2);
        s += __shfl_xor(s, 4);
        s += __shfl_xor(s, 8);
        inv[r] = 1.0f / s;
    }

    // ---- pass 2: recompute, write attn, PV accumulate ----
    f32x4 occ[4];
    #pragma unroll
    for (int j = 0; j < 4; ++j) occ[j] = (f32x4){0.f, 0.f, 0.f, 0.f};
    float* Ob = attn + (((size_t)b * HH + h) * LL + r0 + w * 16) * SS;

    for (int t = 0; t < 16; ++t) {
        __syncthreads();   // prior PV reads of Ks/Vs complete before DMA overwrite
        #pragma unroll
        for (int p = 0; p < 2; ++p) {
            int f = p * 256 + tid;
            int row = f >> 3, seg = f & 7;
            int kb2 = (seg * 8) ^ ((row & 7) * 8);
            gload_lds16(Kp + (size_t)(t * 64 + row) * NH + kb2,
                        (char*)Ks + ((p * 256 + (w << 6)) << 4));
            gload_lds16(Vp + (size_t)row * SS + t * 64 + kb2,
                        (char*)Vs + ((p * 256 + (w << 6)) << 4));
        }
        __syncthreads();
        f32x4 acc[4];
        #pragma unroll
        for (int j = 0; j < 4; ++j) acc[j] = (f32x4){0.f, 0.f, 0.f, 0.f};
        #pragma unroll
        for (int kk = 0; kk < 2; ++kk)
            #pragma unroll
            for (int j = 0; j < 4; ++j) {
                int row = j * 16 + lr;
                bf16x8 bk2 = *(const bf16x8*)&Ks[row * 64 + ((lk * 8 + kk * 32) ^ ((row & 7) * 8))];
                acc[j] = MFMA16(aq[kk], bk2, acc[j]);
            }
        float* Obt = Ob + t * 64;
        #pragma unroll
        for (int j = 0; j < 4; ++j)
            #pragma unroll
            for (int r = 0; r < 4; ++r) {
                int ql = lk * 4 + r;
                float pv = __expf(SM_SCALE * acc[j][r]) * inv[r];
                Obt[(size_t)ql * SS + j * 16 + lr] = pv;
                Psw[ql * 64 + ((j * 16 + lr) ^ ((ql & 7) * 8))] = f2b(pv);
            }
        // per-wave P tile: no block barrier needed (wave-local LDS region)
        #pragma unroll
        for (int kk = 0; kk < 2; ++kk) {
            bf16x8 pa = *(const bf16x8*)&Psw[lr * 64 + ((kk * 32 + lk * 8) ^ ((lr & 7) * 8))];
            #pragma unroll
            for (int j = 0; j < 4; ++j) {
                int row = j * 16 + lr;
                bf16x8 bv2 = *(const bf16x8*)&Vs[row * 64 + ((kk * 32 + lk * 8) ^ ((row & 7) * 8))];
                occ[j] = MFMA16(pa, bv2, occ[j]);
            }
        }
    }

    #pragma unroll
    for (int j = 0; j < 4; ++j)
        #pragma unroll
        for (int r = 0; r < 4; ++r)
            ctx[((size_t)b * LL + r0 + w * 16 + lk * 4 + r) * NH + h * DKH + j * 16 + lr]
                = f2b(occ[j][r]);
}

// ---------------------------------------------------------------------------
// Output projection: out[i][d] = sum_n ctx[i][n]*Wo2[d][n] + b_o[d]
// BM=128, BN=64, BK=64 -> grid (16,32) = 512 blocks (2/CU).
// ---------------------------------------------------------------------------
__global__ __launch_bounds__(256) void out_gemm(
    const ushort_t* __restrict__ A, const ushort_t* __restrict__ B,
    const float* __restrict__ bias, float* __restrict__ C)
{
    __shared__ ushort_t As[128 * 64];
    __shared__ ushort_t Bs[64 * 64];
    const int bn = blockIdx.x * 64;
    const int bm = blockIdx.y * 128;
    const int tid = threadIdx.x;
    const int lane = tid & 63;
    const int w = tid >> 6;
    const int wr = w >> 1, wc = w & 1;
    const int lr = lane & 15, lk = lane >> 4;

    f32x4 acc[4][2];
    #pragma unroll
    for (int i = 0; i < 4; ++i)
        #pragma unroll
        for (int j = 0; j < 2; ++j)
            acc[i][j] = (f32x4){0.f, 0.f, 0.f, 0.f};

    for (int k0 = 0; k0 < 1024; k0 += 64) {
        #pragma unroll
        for (int p = 0; p < 4; ++p) {
            int f = p * 256 + tid;
            int row = f >> 3, seg = f & 7;
            int kb2 = (seg * 8) ^ ((row & 7) * 8);
            gload_lds16(A + (size_t)(bm + row) * 1024 + k0 + kb2,
                        (char*)As + ((p * 256 + (w << 6)) << 4));
        }
        #pragma unroll
        for (int p = 0; p < 2; ++p) {
            int f = p * 256 + tid;
            int row = f >> 3, seg = f & 7;
            int kb2 = (seg * 8) ^ ((row & 7) * 8);
            gload_lds16(B + (size_t)(bn + row) * 1024 + k0 + kb2,
                        (char*)Bs + ((p * 256 + (w << 6)) << 4));
        }
        __syncthreads();
        #pragma unroll
        for (int kk = 0; kk < 2; ++kk) {
            bf16x8 af[4], bfr[2];
            #pragma unroll
            for (int i = 0; i < 4; ++i) {
                int row = wr * 64 + i * 16 + lr;
                af[i] = *(const bf16x8*)&As[row * 64 + ((lk * 8 + kk * 32) ^ ((row & 7) * 8))];
            }
            #pragma unroll
            for (int j = 0; j < 2; ++j) {
                int row = wc * 32 + j * 16 + lr;
                bfr[j] = *(const bf16x8*)&Bs[row * 64 + ((lk * 8 + kk * 32) ^ ((row & 7) * 8))];
            }
            #pragma unroll
            for (int i = 0; i < 4; ++i)
                #pragma unroll
                for (int j = 0; j < 2; ++j)
                    acc[i][j] = MFMA16(af[i], bfr[j], acc[i][j]);
        }
        __syncthreads();
    }

    #pragma unroll
    for (int i = 0; i < 4; ++i)
        #pragma unroll
        for (int j = 0; j < 2; ++j)
            #pragma unroll
            for (int r = 0; r < 4; ++r) {
                int row = bm + wr * 64 + i * 16 + lk * 4 + r;
                int col = bn + wc * 32 + j * 16 + lr;
                C[(size_t)row * DM + col] = acc[i][j][r] + bias[col];
            }
}

// ---------------------------------------------------------------------------
extern "C" void kernel_launch(void* const* d_in, const int* in_sizes, int n_in,
                              void* d_out, int out_size, void* d_ws, size_t ws_size,
                              hipStream_t stream)
{
    const float* queries = (const float*)d_in[0];
    const float* keys    = (const float*)d_in[1];
    const float* values  = (const float*)d_in[2];
    const float* gate    = (const float*)d_in[3];
    const float* W_q     = (const float*)d_in[4];
    const float* b_q     = (const float*)d_in[5];
    const float* W_k     = (const float*)d_in[6];
    const float* b_k     = (const float*)d_in[7];
    const float* W_v     = (const float*)d_in[8];
    const float* b_v     = (const float*)d_in[9];
    const float* W_o     = (const float*)d_in[10];
    const float* b_o     = (const float*)d_in[11];

    float* out  = (float*)d_out;                        // [B,L,DM]
    float* attn = out + (size_t)BB * LL * DM;           // [B,H,L,S]

    char* ws = (char*)d_ws;
    const size_t U = (size_t)8 << 20;
    ushort_t* Xq = (ushort_t*)(ws);
    ushort_t* Xk = (ushort_t*)(ws + 1 * U);
    ushort_t* Xv = (ushort_t*)(ws + 2 * U);
    ushort_t* Gq = (ushort_t*)(ws + 3 * U);
    ushort_t* Gk = (ushort_t*)(ws + 4 * U);
    ushort_t* Gv = (ushort_t*)(ws + 5 * U);
    ushort_t* Vt = (ushort_t*)(ws + 6 * U);
    const bool big = ws_size >= 9 * U + ((size_t)2 << 20);
    ushort_t *Qb, *Kb, *Wo2;
    if (big) { Qb = (ushort_t*)(ws + 7 * U); Kb = (ushort_t*)(ws + 8 * U); Wo2 = (ushort_t*)(ws + 9 * U); }
    else     { Qb = Xv; Kb = Gv; Wo2 = (ushort_t*)(ws + 7 * U); }
    ushort_t* ctx = Xq;     // Xq dead after Q-GEMM

    dim3 blk(256, 1, 1);
    prep_kernel<<<2048, blk, 0, stream>>>(queries, keys, values, gate,
                                          W_q, W_k, W_v, W_o,
                                          Xq, Xk, Xv, Gq, Gk, Gv, Wo2);
    if (big) {
        qkv_gemm<<<dim3(8, 8, 12), blk, 0, stream>>>(Xq, Gq, b_q, Xk, Gk, b_k,
                                                     Xv, Gv, b_v, Qb, Kb, Vt, 0);
    } else {
        // Vt first (reads Xv,Gv), then Q/K merged writing into dead Xv/Gv slots
        qkv_gemm<<<dim3(8, 8, 4), blk, 0, stream>>>(Xq, Gq, b_q, Xk, Gk, b_k,
                                                    Xv, Gv, b_v, Qb, Kb, Vt, 2);
        qkv_gemm<<<dim3(8, 8, 8), blk, 0, stream>>>(Xq, Gq, b_q, Xk, Gk, b_k,
                                                    Xv, Gv, b_v, Qb, Kb, Vt, 1);
    }
    fused_attn_kernel<<<dim3(16, 16, 4), blk, 0, stream>>>(Qb, Kb, Vt, attn, ctx);
    out_gemm<<<dim3(16, 32, 1), blk, 0, stream>>>(ctx, Wo2, b_o, out);
}

// Round 4
// 182.286 us; speedup vs baseline: 4.6271x; 1.0767x over previous
//
#include <hip/hip_runtime.h>
#include <math.h>

#define BB 4
#define LL 1024
#define SS 1024
#define DM 1024
#define HH 16
#define DKH 64
#define NH 1024
#define SM_SCALE 0.125f

typedef __attribute__((ext_vector_type(8))) short bf16x8;
typedef __attribute__((ext_vector_type(4))) float f32x4;
typedef unsigned short ushort_t;
typedef unsigned int uint_t;

#define MFMA16(a, b, c) __builtin_amdgcn_mfma_f32_16x16x32_bf16((a), (b), (c), 0, 0, 0)

__device__ __forceinline__ ushort_t f2b(float f) {
    union { float f; uint_t u; } x; x.f = f;
    uint_t r = x.u + 0x7fffu + ((x.u >> 16) & 1u);   // RNE to bf16
    return (ushort_t)(r >> 16);
}

__device__ __forceinline__ void gload_lds16(const void* g, void* l) {
    __builtin_amdgcn_global_load_lds(
        (const __attribute__((address_space(1))) unsigned int*)g,
        (__attribute__((address_space(3))) unsigned int*)l, 16, 0, 0);
}

// Bijective XCD swizzle (nwg % 8 == 0): blocks with equal (lin%8) — same XCD
// under round-robin dispatch — get a contiguous work chunk [k*nwg/8, ...).
__device__ __forceinline__ int xcd_swz(int lin, int nwg) {
    return (lin & 7) * (nwg >> 3) + (lin >> 3);
}

// ---------------------------------------------------------------------------
// Prep: fp32 -> bf16; gate read ONCE serving all three gated weights.
// ---------------------------------------------------------------------------
__device__ __forceinline__ void cvt8(const float* src, ushort_t* dst, const float* g2) {
    float4 a  = *(const float4*)(src);
    float4 b4 = *(const float4*)(src + 4);
    if (g2) {
        float4 ga = *(const float4*)(g2);
        float4 gb = *(const float4*)(g2 + 4);
        a.x *= ga.x; a.y *= ga.y; a.z *= ga.z; a.w *= ga.w;
        b4.x *= gb.x; b4.y *= gb.y; b4.z *= gb.z; b4.w *= gb.w;
    }
    uint4 o;
    o.x = f2b(a.x)  | ((uint_t)f2b(a.y)  << 16);
    o.y = f2b(a.z)  | ((uint_t)f2b(a.w)  << 16);
    o.z = f2b(b4.x) | ((uint_t)f2b(b4.y) << 16);
    o.w = f2b(b4.z) | ((uint_t)f2b(b4.w) << 16);
    *(uint4*)dst = o;
}

__global__ __launch_bounds__(256) void prep_kernel(
    const float* __restrict__ q, const float* __restrict__ k, const float* __restrict__ v,
    const float* __restrict__ gate,
    const float* __restrict__ Wq, const float* __restrict__ Wk, const float* __restrict__ Wv,
    const float* __restrict__ Wo,
    ushort_t* __restrict__ Xq, ushort_t* __restrict__ Xk, ushort_t* __restrict__ Xv,
    ushort_t* __restrict__ Gq, ushort_t* __restrict__ Gk, ushort_t* __restrict__ Gv,
    ushort_t* __restrict__ Wo2)
{
    const int XCH = 3 * 524288;
    const int GCH = 524288;
    const int WCH = 131072;
    for (int c = blockIdx.x * 256 + threadIdx.x; c < XCH + GCH + WCH; c += gridDim.x * 256) {
        if (c < XCH) {
            int r = c >> 19;
            int e = (c & 524287) * 8;
            cvt8((r == 0 ? q : r == 1 ? k : v) + e,
                 (r == 0 ? Xq : r == 1 ? Xk : Xv) + e, nullptr);
        } else if (c < XCH + GCH) {
            int e = (c - XCH) * 8;          // e = b*1048576 + nm
            int nm = e & 1048575;
            const float* g2 = gate + e;
            cvt8(Wq + nm, Gq + e, g2);
            cvt8(Wk + nm, Gk + e, g2);
            cvt8(Wv + nm, Gv + e, g2);
        } else {
            int e = (c - XCH - GCH) * 8;
            cvt8(Wo + e, Wo2 + e, nullptr);
        }
    }
}

// ---------------------------------------------------------------------------
// Merged Q/K/Vt GEMM, 1-D grid + XCD chunking. 128x128 tile, BK=64, 4 waves.
//   g=0: Qb[b][l][n] = Xq[l]·Gq[n] + bq[n]       (bias col)
//   g=1: Kb[b][s][n] = Xk[s]·Gk[n] + bk[n]       (bias col)
//   g=2: Vt[b][n][s] = Gv[n]·Xv[s] + bv[n]       (bias row)
// mode 0: 12 instances (b*3+g); mode 1: 8 (b*2+g, g<2); mode 2: 4 (b, g=2).
// Within-instance: bm-major (8 consecutive blocks share the A-panel; B panel
// stays L2-resident across bm rows).
// ---------------------------------------------------------------------------
__global__ __launch_bounds__(256) void qkv_gemm(
    const ushort_t* __restrict__ Xq, const ushort_t* __restrict__ Gq, const float* __restrict__ bq,
    const ushort_t* __restrict__ Xk, const ushort_t* __restrict__ Gk, const float* __restrict__ bk,
    const ushort_t* __restrict__ Xv, const ushort_t* __restrict__ Gv, const float* __restrict__ bv,
    ushort_t* __restrict__ Qb, ushort_t* __restrict__ Kb, ushort_t* __restrict__ Vt,
    int mode)
{
    __shared__ ushort_t As[128 * 64];
    __shared__ ushort_t Bs[128 * 64];
    const int p  = xcd_swz(blockIdx.x, gridDim.x);
    const int g2 = p >> 6;
    const int r  = p & 63;
    int b, g;
    if (mode == 0)      { b = g2 / 3;  g = g2 % 3; }
    else if (mode == 1) { b = g2 >> 1; g = g2 & 1; }
    else                { b = g2;      g = 2;      }
    const size_t off = (size_t)b * 1048576;
    const ushort_t *A, *B; const float* bias; ushort_t* C; bool brow;
    if (g == 0)      { A = Xq + off; B = Gq + off; bias = bq; C = Qb + off; brow = false; }
    else if (g == 1) { A = Xk + off; B = Gk + off; bias = bk; C = Kb + off; brow = false; }
    else             { A = Gv + off; B = Xv + off; bias = bv; C = Vt + off; brow = true;  }

    const int bm = (r >> 3) * 128;
    const int bn = (r & 7) * 128;
    const int tid = threadIdx.x;
    const int lane = tid & 63;
    const int w = tid >> 6;
    const int wr = w >> 1, wc = w & 1;
    const int lr = lane & 15, lk = lane >> 4;

    f32x4 acc[4][4];
    #pragma unroll
    for (int i = 0; i < 4; ++i)
        #pragma unroll
        for (int j = 0; j < 4; ++j)
            acc[i][j] = (f32x4){0.f, 0.f, 0.f, 0.f};

    for (int k0 = 0; k0 < 1024; k0 += 64) {
        #pragma unroll
        for (int pp = 0; pp < 4; ++pp) {
            int f = pp * 256 + tid;
            int row = f >> 3, seg = f & 7;
            int kb2 = (seg * 8) ^ ((row & 7) * 8);
            gload_lds16(A + (size_t)(bm + row) * 1024 + k0 + kb2,
                        (char*)As + ((pp * 256 + (w << 6)) << 4));
            gload_lds16(B + (size_t)(bn + row) * 1024 + k0 + kb2,
                        (char*)Bs + ((pp * 256 + (w << 6)) << 4));
        }
        __syncthreads();
        #pragma unroll
        for (int kk = 0; kk < 2; ++kk) {
            bf16x8 af[4], bfr[4];
            #pragma unroll
            for (int i = 0; i < 4; ++i) {
                int row = wr * 64 + i * 16 + lr;
                af[i] = *(const bf16x8*)&As[row * 64 + ((lk * 8 + kk * 32) ^ ((row & 7) * 8))];
            }
            #pragma unroll
            for (int j = 0; j < 4; ++j) {
                int row = wc * 64 + j * 16 + lr;
                bfr[j] = *(const bf16x8*)&Bs[row * 64 + ((lk * 8 + kk * 32) ^ ((row & 7) * 8))];
            }
            #pragma unroll
            for (int i = 0; i < 4; ++i)
                #pragma unroll
                for (int j = 0; j < 4; ++j)
                    acc[i][j] = MFMA16(af[i], bfr[j], acc[i][j]);
        }
        __syncthreads();
    }

    #pragma unroll
    for (int i = 0; i < 4; ++i)
        #pragma unroll
        for (int j = 0; j < 4; ++j)
            #pragma unroll
            for (int rr = 0; rr < 4; ++rr) {
                int row = bm + wr * 64 + i * 16 + lk * 4 + rr;
                int col = bn + wc * 64 + j * 16 + lr;
                float vv = acc[i][j][rr] + bias[brow ? row : col];
                C[(size_t)row * 1024 + col] = f2b(vv);
            }
}

// ---------------------------------------------------------------------------
// Fused QK^T + softmax + attn-write + PV. 1-D grid + XCD chunking:
// each XCD owns 8 complete (b,h) pairs (K/V read once chip-wide).
// ---------------------------------------------------------------------------
__global__ __launch_bounds__(256) void fused_attn_kernel(
    const ushort_t* __restrict__ Q, const ushort_t* __restrict__ Kmat,
    const ushort_t* __restrict__ Vt, float* __restrict__ attn,
    ushort_t* __restrict__ ctx)
{
    __shared__ ushort_t Ks[64 * 64];
    __shared__ ushort_t Vs[64 * 64];
    __shared__ ushort_t Ps[64 * 64];
    const int p  = xcd_swz(blockIdx.x, gridDim.x);
    const int bh = p >> 4;
    const int b  = bh >> 4;
    const int h  = bh & 15;
    const int r0 = (p & 15) * 64;
    const int tid = threadIdx.x, lane = tid & 63, w = tid >> 6;
    const int lr = lane & 15, lk = lane >> 4;

    bf16x8 aq[2];
    {
        const ushort_t* Qrow = Q + ((size_t)b * LL + r0 + w * 16 + lr) * NH + h * DKH;
        aq[0] = *(const bf16x8*)(Qrow + lk * 8);
        aq[1] = *(const bf16x8*)(Qrow + lk * 8 + 32);
    }
    const ushort_t* Kp = Kmat + (size_t)b * SS * NH + h * DKH;       // [s][dk], stride NH
    const ushort_t* Vp = Vt + ((size_t)b * NH + h * DKH) * SS;       // [dk][s], stride SS
    ushort_t* Psw = Ps + w * 1024;

    float inv[4] = {0.f, 0.f, 0.f, 0.f};

    // ---- pass 1: exp-sums ----
    for (int t = 0; t < 16; ++t) {
        __syncthreads();
        #pragma unroll
        for (int pp = 0; pp < 2; ++pp) {
            int f = pp * 256 + tid;
            int row = f >> 3, seg = f & 7;
            int kb2 = (seg * 8) ^ ((row & 7) * 8);
            gload_lds16(Kp + (size_t)(t * 64 + row) * NH + kb2,
                        (char*)Ks + ((pp * 256 + (w << 6)) << 4));
        }
        __syncthreads();
        f32x4 acc[4];
        #pragma unroll
        for (int j = 0; j < 4; ++j) acc[j] = (f32x4){0.f, 0.f, 0.f, 0.f};
        #pragma unroll
        for (int kk = 0; kk < 2; ++kk)
            #pragma unroll
            for (int j = 0; j < 4; ++j) {
                int row = j * 16 + lr;
                bf16x8 bk2 = *(const bf16x8*)&Ks[row * 64 + ((lk * 8 + kk * 32) ^ ((row & 7) * 8))];
                acc[j] = MFMA16(aq[kk], bk2, acc[j]);
            }
        #pragma unroll
        for (int rr = 0; rr < 4; ++rr)
            inv[rr] += __expf(SM_SCALE * acc[0][rr]) + __expf(SM_SCALE * acc[1][rr])
                     + __expf(SM_SCALE * acc[2][rr]) + __expf(SM_SCALE * acc[3][rr]);
    }
    #pragma unroll
    for (int rr = 0; rr < 4; ++rr) {
        float s = inv[rr];
        s += __shfl_xor(s, 1);
        s += __shfl_xor(s, 2);
        s += __shfl_xor(s, 4);
        s += __shfl_xor(s, 8);
        inv[rr] = 1.0f / s;
    }

    // ---- pass 2: recompute, write attn, PV accumulate ----
    f32x4 occ[4];
    #pragma unroll
    for (int j = 0; j < 4; ++j) occ[j] = (f32x4){0.f, 0.f, 0.f, 0.f};
    float* Ob = attn + (((size_t)b * HH + h) * LL + r0 + w * 16) * SS;

    for (int t = 0; t < 16; ++t) {
        __syncthreads();   // prior PV reads of Ks/Vs complete before DMA overwrite
        #pragma unroll
        for (int pp = 0; pp < 2; ++pp) {
            int f = pp * 256 + tid;
            int row = f >> 3, seg = f & 7;
            int kb2 = (seg * 8) ^ ((row & 7) * 8);
            gload_lds16(Kp + (size_t)(t * 64 + row) * NH + kb2,
                        (char*)Ks + ((pp * 256 + (w << 6)) << 4));
            gload_lds16(Vp + (size_t)row * SS + t * 64 + kb2,
                        (char*)Vs + ((pp * 256 + (w << 6)) << 4));
        }
        __syncthreads();
        f32x4 acc[4];
        #pragma unroll
        for (int j = 0; j < 4; ++j) acc[j] = (f32x4){0.f, 0.f, 0.f, 0.f};
        #pragma unroll
        for (int kk = 0; kk < 2; ++kk)
            #pragma unroll
            for (int j = 0; j < 4; ++j) {
                int row = j * 16 + lr;
                bf16x8 bk2 = *(const bf16x8*)&Ks[row * 64 + ((lk * 8 + kk * 32) ^ ((row & 7) * 8))];
                acc[j] = MFMA16(aq[kk], bk2, acc[j]);
            }
        float* Obt = Ob + t * 64;
        #pragma unroll
        for (int j = 0; j < 4; ++j)
            #pragma unroll
            for (int rr = 0; rr < 4; ++rr) {
                int ql = lk * 4 + rr;
                float pv = __expf(SM_SCALE * acc[j][rr]) * inv[rr];
                Obt[(size_t)ql * SS + j * 16 + lr] = pv;
                Psw[ql * 64 + ((j * 16 + lr) ^ ((ql & 7) * 8))] = f2b(pv);
            }
        // per-wave P tile: no block barrier needed (wave-local LDS region)
        #pragma unroll
        for (int kk = 0; kk < 2; ++kk) {
            bf16x8 pa = *(const bf16x8*)&Psw[lr * 64 + ((kk * 32 + lk * 8) ^ ((lr & 7) * 8))];
            #pragma unroll
            for (int j = 0; j < 4; ++j) {
                int row = j * 16 + lr;
                bf16x8 bv2 = *(const bf16x8*)&Vs[row * 64 + ((kk * 32 + lk * 8) ^ ((row & 7) * 8))];
                occ[j] = MFMA16(pa, bv2, occ[j]);
            }
        }
    }

    #pragma unroll
    for (int j = 0; j < 4; ++j)
        #pragma unroll
        for (int rr = 0; rr < 4; ++rr)
            ctx[((size_t)b * LL + r0 + w * 16 + lk * 4 + rr) * NH + h * DKH + j * 16 + lr]
                = f2b(occ[j][rr]);
}

// ---------------------------------------------------------------------------
// Output projection: out[i][d] = sum_n ctx[i][n]*Wo2[d][n] + b_o[d]
// 1-D grid + XCD chunking: XCD k owns bm in [4k,4k+4) x all bn
// (A slice 1 MB + full B 2 MB fits the 4 MB per-XCD L2).
// ---------------------------------------------------------------------------
__global__ __launch_bounds__(256) void out_gemm(
    const ushort_t* __restrict__ A, const ushort_t* __restrict__ B,
    const float* __restrict__ bias, float* __restrict__ C)
{
    __shared__ ushort_t As[128 * 64];
    __shared__ ushort_t Bs[64 * 64];
    const int p  = xcd_swz(blockIdx.x, gridDim.x);
    const int bm = (p >> 4) * 128;
    const int bn = (p & 15) * 64;
    const int tid = threadIdx.x;
    const int lane = tid & 63;
    const int w = tid >> 6;
    const int wr = w >> 1, wc = w & 1;
    const int lr = lane & 15, lk = lane >> 4;

    f32x4 acc[4][2];
    #pragma unroll
    for (int i = 0; i < 4; ++i)
        #pragma unroll
        for (int j = 0; j < 2; ++j)
            acc[i][j] = (f32x4){0.f, 0.f, 0.f, 0.f};

    for (int k0 = 0; k0 < 1024; k0 += 64) {
        #pragma unroll
        for (int pp = 0; pp < 4; ++pp) {
            int f = pp * 256 + tid;
            int row = f >> 3, seg = f & 7;
            int kb2 = (seg * 8) ^ ((row & 7) * 8);
            gload_lds16(A + (size_t)(bm + row) * 1024 + k0 + kb2,
                        (char*)As + ((pp * 256 + (w << 6)) << 4));
        }
        #pragma unroll
        for (int pp = 0; pp < 2; ++pp) {
            int f = pp * 256 + tid;
            int row = f >> 3, seg = f & 7;
            int kb2 = (seg * 8) ^ ((row & 7) * 8);
            gload_lds16(B + (size_t)(bn + row) * 1024 + k0 + kb2,
                        (char*)Bs + ((pp * 256 + (w << 6)) << 4));
        }
        __syncthreads();
        #pragma unroll
        for (int kk = 0; kk < 2; ++kk) {
            bf16x8 af[4], bfr[2];
            #pragma unroll
            for (int i = 0; i < 4; ++i) {
                int row = wr * 64 + i * 16 + lr;
                af[i] = *(const bf16x8*)&As[row * 64 + ((lk * 8 + kk * 32) ^ ((row & 7) * 8))];
            }
            #pragma unroll
            for (int j = 0; j < 2; ++j) {
                int row = wc * 32 + j * 16 + lr;
                bfr[j] = *(const bf16x8*)&Bs[row * 64 + ((lk * 8 + kk * 32) ^ ((row & 7) * 8))];
            }
            #pragma unroll
            for (int i = 0; i < 4; ++i)
                #pragma unroll
                for (int j = 0; j < 2; ++j)
                    acc[i][j] = MFMA16(af[i], bfr[j], acc[i][j]);
        }
        __syncthreads();
    }

    #pragma unroll
    for (int i = 0; i < 4; ++i)
        #pragma unroll
        for (int j = 0; j < 2; ++j)
            #pragma unroll
            for (int rr = 0; rr < 4; ++rr) {
                int row = bm + wr * 64 + i * 16 + lk * 4 + rr;
                int col = bn + wc * 32 + j * 16 + lr;
                C[(size_t)row * DM + col] = acc[i][j][rr] + bias[col];
            }
}

// ---------------------------------------------------------------------------
extern "C" void kernel_launch(void* const* d_in, const int* in_sizes, int n_in,
                              void* d_out, int out_size, void* d_ws, size_t ws_size,
                              hipStream_t stream)
{
    const float* queries = (const float*)d_in[0];
    const float* keys    = (const float*)d_in[1];
    const float* values  = (const float*)d_in[2];
    const float* gate    = (const float*)d_in[3];
    const float* W_q     = (const float*)d_in[4];
    const float* b_q     = (const float*)d_in[5];
    const float* W_k     = (const float*)d_in[6];
    const float* b_k     = (const float*)d_in[7];
    const float* W_v     = (const float*)d_in[8];
    const float* b_v     = (const float*)d_in[9];
    const float* W_o     = (const float*)d_in[10];
    const float* b_o     = (const float*)d_in[11];

    float* out  = (float*)d_out;                        // [B,L,DM]
    float* attn = out + (size_t)BB * LL * DM;           // [B,H,L,S]

    char* ws = (char*)d_ws;
    const size_t U = (size_t)8 << 20;
    ushort_t* Xq = (ushort_t*)(ws);
    ushort_t* Xk = (ushort_t*)(ws + 1 * U);
    ushort_t* Xv = (ushort_t*)(ws + 2 * U);
    ushort_t* Gq = (ushort_t*)(ws + 3 * U);
    ushort_t* Gk = (ushort_t*)(ws + 4 * U);
    ushort_t* Gv = (ushort_t*)(ws + 5 * U);
    ushort_t* Vt = (ushort_t*)(ws + 6 * U);
    const bool big = ws_size >= 9 * U + ((size_t)2 << 20);
    ushort_t *Qb, *Kb, *Wo2;
    if (big) { Qb = (ushort_t*)(ws + 7 * U); Kb = (ushort_t*)(ws + 8 * U); Wo2 = (ushort_t*)(ws + 9 * U); }
    else     { Qb = Xv; Kb = Gv; Wo2 = (ushort_t*)(ws + 7 * U); }
    ushort_t* ctx = Xq;     // Xq dead after Q-GEMM

    dim3 blk(256, 1, 1);
    prep_kernel<<<2048, blk, 0, stream>>>(queries, keys, values, gate,
                                          W_q, W_k, W_v, W_o,
                                          Xq, Xk, Xv, Gq, Gk, Gv, Wo2);
    if (big) {
        qkv_gemm<<<768, blk, 0, stream>>>(Xq, Gq, b_q, Xk, Gk, b_k,
                                          Xv, Gv, b_v, Qb, Kb, Vt, 0);
    } else {
        // Vt first (reads Xv,Gv), then Q/K merged writing into dead Xv/Gv slots
        qkv_gemm<<<256, blk, 0, stream>>>(Xq, Gq, b_q, Xk, Gk, b_k,
                                          Xv, Gv, b_v, Qb, Kb, Vt, 2);
        qkv_gemm<<<512, blk, 0, stream>>>(Xq, Gq, b_q, Xk, Gk, b_k,
                                          Xv, Gv, b_v, Qb, Kb, Vt, 1);
    }
    fused_attn_kernel<<<1024, blk, 0, stream>>>(Qb, Kb, Vt, attn, ctx);
    out_gemm<<<512, blk, 0, stream>>>(ctx, Wo2, b_o, out);
}

// Round 5
// 178.178 us; speedup vs baseline: 4.7338x; 1.0231x over previous
//
#include <hip/hip_runtime.h>
#include <math.h>

#define BB 4
#define LL 1024
#define SS 1024
#define DM 1024
#define HH 16
#define DKH 64
#define NH 1024
#define SM_SCALE 0.125f

typedef __attribute__((ext_vector_type(8))) short bf16x8;
typedef __attribute__((ext_vector_type(4))) float f32x4;
typedef unsigned short ushort_t;
typedef unsigned int uint_t;

#define MFMA16(a, b, c) __builtin_amdgcn_mfma_f32_16x16x32_bf16((a), (b), (c), 0, 0, 0)

__device__ __forceinline__ ushort_t f2b(float f) {
    union { float f; uint_t u; } x; x.f = f;
    uint_t r = x.u + 0x7fffu + ((x.u >> 16) & 1u);   // RNE to bf16
    return (ushort_t)(r >> 16);
}

__device__ __forceinline__ float b2f(ushort_t v) {
    union { float f; uint_t u; } x; x.u = ((uint_t)v) << 16;
    return x.f;
}

__device__ __forceinline__ void gload_lds16(const void* g, void* l) {
    __builtin_amdgcn_global_load_lds(
        (const __attribute__((address_space(1))) unsigned int*)g,
        (__attribute__((address_space(3))) unsigned int*)l, 16, 0, 0);
}

// Bijective XCD swizzle (nwg % 8 == 0): blocks with equal (lin%8) — same XCD
// under round-robin dispatch — get a contiguous work chunk [k*nwg/8, ...).
__device__ __forceinline__ int xcd_swz(int lin, int nwg) {
    return (lin & 7) * (nwg >> 3) + (lin >> 3);
}

// ---------------------------------------------------------------------------
// Prep: fp32 -> bf16; gate read ONCE serving all three gated weights.
// ---------------------------------------------------------------------------
__device__ __forceinline__ void cvt8(const float* src, ushort_t* dst, const float* g2) {
    float4 a  = *(const float4*)(src);
    float4 b4 = *(const float4*)(src + 4);
    if (g2) {
        float4 ga = *(const float4*)(g2);
        float4 gb = *(const float4*)(g2 + 4);
        a.x *= ga.x; a.y *= ga.y; a.z *= ga.z; a.w *= ga.w;
        b4.x *= gb.x; b4.y *= gb.y; b4.z *= gb.z; b4.w *= gb.w;
    }
    uint4 o;
    o.x = f2b(a.x)  | ((uint_t)f2b(a.y)  << 16);
    o.y = f2b(a.z)  | ((uint_t)f2b(a.w)  << 16);
    o.z = f2b(b4.x) | ((uint_t)f2b(b4.y) << 16);
    o.w = f2b(b4.z) | ((uint_t)f2b(b4.w) << 16);
    *(uint4*)dst = o;
}

__global__ __launch_bounds__(256) void prep_kernel(
    const float* __restrict__ q, const float* __restrict__ k, const float* __restrict__ v,
    const float* __restrict__ gate,
    const float* __restrict__ Wq, const float* __restrict__ Wk, const float* __restrict__ Wv,
    const float* __restrict__ Wo,
    ushort_t* __restrict__ Xq, ushort_t* __restrict__ Xk, ushort_t* __restrict__ Xv,
    ushort_t* __restrict__ Gq, ushort_t* __restrict__ Gk, ushort_t* __restrict__ Gv,
    ushort_t* __restrict__ Wo2)
{
    const int XCH = 3 * 524288;
    const int GCH = 524288;
    const int WCH = 131072;
    for (int c = blockIdx.x * 256 + threadIdx.x; c < XCH + GCH + WCH; c += gridDim.x * 256) {
        if (c < XCH) {
            int r = c >> 19;
            int e = (c & 524287) * 8;
            cvt8((r == 0 ? q : r == 1 ? k : v) + e,
                 (r == 0 ? Xq : r == 1 ? Xk : Xv) + e, nullptr);
        } else if (c < XCH + GCH) {
            int e = (c - XCH) * 8;          // e = b*1048576 + nm
            int nm = e & 1048575;
            const float* g2 = gate + e;
            cvt8(Wq + nm, Gq + e, g2);
            cvt8(Wk + nm, Gk + e, g2);
            cvt8(Wv + nm, Gv + e, g2);
        } else {
            int e = (c - XCH - GCH) * 8;
            cvt8(Wo + e, Wo2 + e, nullptr);
        }
    }
}

// ---------------------------------------------------------------------------
// Merged Q/K/Vt GEMM, 1-D grid + XCD chunking. 128x128 tile, BK=64, 4 waves.
// (unchanged known-good m97 structure)
// ---------------------------------------------------------------------------
__global__ __launch_bounds__(256) void qkv_gemm(
    const ushort_t* __restrict__ Xq, const ushort_t* __restrict__ Gq, const float* __restrict__ bq,
    const ushort_t* __restrict__ Xk, const ushort_t* __restrict__ Gk, const float* __restrict__ bk,
    const ushort_t* __restrict__ Xv, const ushort_t* __restrict__ Gv, const float* __restrict__ bv,
    ushort_t* __restrict__ Qb, ushort_t* __restrict__ Kb, ushort_t* __restrict__ Vt,
    int mode)
{
    __shared__ ushort_t As[128 * 64];
    __shared__ ushort_t Bs[128 * 64];
    const int p  = xcd_swz(blockIdx.x, gridDim.x);
    const int g2 = p >> 6;
    const int r  = p & 63;
    int b, g;
    if (mode == 0)      { b = g2 / 3;  g = g2 % 3; }
    else if (mode == 1) { b = g2 >> 1; g = g2 & 1; }
    else                { b = g2;      g = 2;      }
    const size_t off = (size_t)b * 1048576;
    const ushort_t *A, *B; const float* bias; ushort_t* C; bool brow;
    if (g == 0)      { A = Xq + off; B = Gq + off; bias = bq; C = Qb + off; brow = false; }
    else if (g == 1) { A = Xk + off; B = Gk + off; bias = bk; C = Kb + off; brow = false; }
    else             { A = Gv + off; B = Xv + off; bias = bv; C = Vt + off; brow = true;  }

    const int bm = (r >> 3) * 128;
    const int bn = (r & 7) * 128;
    const int tid = threadIdx.x;
    const int lane = tid & 63;
    const int w = tid >> 6;
    const int wr = w >> 1, wc = w & 1;
    const int lr = lane & 15, lk = lane >> 4;

    f32x4 acc[4][4];
    #pragma unroll
    for (int i = 0; i < 4; ++i)
        #pragma unroll
        for (int j = 0; j < 4; ++j)
            acc[i][j] = (f32x4){0.f, 0.f, 0.f, 0.f};

    for (int k0 = 0; k0 < 1024; k0 += 64) {
        #pragma unroll
        for (int pp = 0; pp < 4; ++pp) {
            int f = pp * 256 + tid;
            int row = f >> 3, seg = f & 7;
            int kb2 = (seg * 8) ^ ((row & 7) * 8);
            gload_lds16(A + (size_t)(bm + row) * 1024 + k0 + kb2,
                        (char*)As + ((pp * 256 + (w << 6)) << 4));
            gload_lds16(B + (size_t)(bn + row) * 1024 + k0 + kb2,
                        (char*)Bs + ((pp * 256 + (w << 6)) << 4));
        }
        __syncthreads();
        #pragma unroll
        for (int kk = 0; kk < 2; ++kk) {
            bf16x8 af[4], bfr[4];
            #pragma unroll
            for (int i = 0; i < 4; ++i) {
                int row = wr * 64 + i * 16 + lr;
                af[i] = *(const bf16x8*)&As[row * 64 + ((lk * 8 + kk * 32) ^ ((row & 7) * 8))];
            }
            #pragma unroll
            for (int j = 0; j < 4; ++j) {
                int row = wc * 64 + j * 16 + lr;
                bfr[j] = *(const bf16x8*)&Bs[row * 64 + ((lk * 8 + kk * 32) ^ ((row & 7) * 8))];
            }
            #pragma unroll
            for (int i = 0; i < 4; ++i)
                #pragma unroll
                for (int j = 0; j < 4; ++j)
                    acc[i][j] = MFMA16(af[i], bfr[j], acc[i][j]);
        }
        __syncthreads();
    }

    #pragma unroll
    for (int i = 0; i < 4; ++i)
        #pragma unroll
        for (int j = 0; j < 4; ++j)
            #pragma unroll
            for (int rr = 0; rr < 4; ++rr) {
                int row = bm + wr * 64 + i * 16 + lk * 4 + rr;
                int col = bn + wc * 64 + j * 16 + lr;
                float vv = acc[i][j][rr] + bias[brow ? row : col];
                C[(size_t)row * 1024 + col] = f2b(vv);
            }
}

// ---------------------------------------------------------------------------
// Fused QK^T + softmax + attn-write + PV, 2-phase pipelined staging:
// double-buffered Ks/Vs; stage(t+1) issued BEFORE compute(t); one barrier/iter
// (the __syncthreads vmcnt(0) drain lands AFTER compute — DMA ∥ MFMA+exp).
// attn emitted from the bf16 Psw tile via float4 stores (4 instrs vs 16).
// LDS: 2*8 + 2*8 + 8 = 40KB -> 4 blocks/CU (160KB exactly).
// ---------------------------------------------------------------------------
__global__ __launch_bounds__(256) void fused_attn_kernel(
    const ushort_t* __restrict__ Q, const ushort_t* __restrict__ Kmat,
    const ushort_t* __restrict__ Vt, float* __restrict__ attn,
    ushort_t* __restrict__ ctx)
{
    __shared__ ushort_t Ks[2][64 * 64];
    __shared__ ushort_t Vs[2][64 * 64];
    __shared__ ushort_t Ps[64 * 64];
    const int p  = xcd_swz(blockIdx.x, gridDim.x);
    const int bh = p >> 4;
    const int b  = bh >> 4;
    const int h  = bh & 15;
    const int r0 = (p & 15) * 64;
    const int tid = threadIdx.x, lane = tid & 63, w = tid >> 6;
    const int lr = lane & 15, lk = lane >> 4;

    bf16x8 aq[2];
    {
        const ushort_t* Qrow = Q + ((size_t)b * LL + r0 + w * 16 + lr) * NH + h * DKH;
        aq[0] = *(const bf16x8*)(Qrow + lk * 8);
        aq[1] = *(const bf16x8*)(Qrow + lk * 8 + 32);
    }
    const ushort_t* Kp = Kmat + (size_t)b * SS * NH + h * DKH;       // [s][dk], stride NH
    const ushort_t* Vp = Vt + ((size_t)b * NH + h * DKH) * SS;       // [dk][s], stride SS
    ushort_t* Psw = Ps + w * 1024;

    // staging helpers (per-thread lane mapping identical to R4)
    const int srow = tid >> 3;           // 0..31 (+32 for pp=1)
    const int sseg = tid & 7;
    const int skb  = (sseg * 8) ^ ((srow & 7) * 8);
    const int skb1 = (sseg * 8) ^ (((srow + 32) & 7) * 8);

#define STAGE_K(t, buf)                                                          \
    do {                                                                         \
        gload_lds16(Kp + (size_t)((t) * 64 + srow) * NH + skb,                   \
                    (char*)(&Ks[buf][0]) + ((0 * 256 + (w << 6)) << 4));         \
        gload_lds16(Kp + (size_t)((t) * 64 + srow + 32) * NH + skb1,             \
                    (char*)(&Ks[buf][0]) + ((1 * 256 + (w << 6)) << 4));         \
    } while (0)
#define STAGE_V(t, buf)                                                          \
    do {                                                                         \
        gload_lds16(Vp + (size_t)srow * SS + (t) * 64 + skb,                     \
                    (char*)(&Vs[buf][0]) + ((0 * 256 + (w << 6)) << 4));         \
        gload_lds16(Vp + (size_t)(srow + 32) * SS + (t) * 64 + skb1,             \
                    (char*)(&Vs[buf][0]) + ((1 * 256 + (w << 6)) << 4));         \
    } while (0)

    float inv[4] = {0.f, 0.f, 0.f, 0.f};

    // ---- pass 1: exp-sums ----
    STAGE_K(0, 0);
    __syncthreads();
    for (int t = 0; t < 16; ++t) {
        const int cur = t & 1;
        if (t < 15) STAGE_K(t + 1, cur ^ 1);
        f32x4 acc[4];
        #pragma unroll
        for (int j = 0; j < 4; ++j) acc[j] = (f32x4){0.f, 0.f, 0.f, 0.f};
        #pragma unroll
        for (int kk = 0; kk < 2; ++kk)
            #pragma unroll
            for (int j = 0; j < 4; ++j) {
                int row = j * 16 + lr;
                bf16x8 bk2 = *(const bf16x8*)&Ks[cur][row * 64 + ((lk * 8 + kk * 32) ^ ((row & 7) * 8))];
                acc[j] = MFMA16(aq[kk], bk2, acc[j]);
            }
        #pragma unroll
        for (int rr = 0; rr < 4; ++rr)
            inv[rr] += __expf(SM_SCALE * acc[0][rr]) + __expf(SM_SCALE * acc[1][rr])
                     + __expf(SM_SCALE * acc[2][rr]) + __expf(SM_SCALE * acc[3][rr]);
        __syncthreads();
    }
    #pragma unroll
    for (int rr = 0; rr < 4; ++rr) {
        float s = inv[rr];
        s += __shfl_xor(s, 1);
        s += __shfl_xor(s, 2);
        s += __shfl_xor(s, 4);
        s += __shfl_xor(s, 8);
        inv[rr] = 1.0f / s;
    }

    // ---- pass 2: recompute, PV accumulate, emit attn from Psw ----
    f32x4 occ[4];
    #pragma unroll
    for (int j = 0; j < 4; ++j) occ[j] = (f32x4){0.f, 0.f, 0.f, 0.f};
    float* Ob = attn + (((size_t)b * HH + h) * LL + r0 + w * 16) * SS;
    const int erow = lane >> 3;          // 0..7, +8 second half
    const int eseg = lane & 7;

    STAGE_K(0, 0);
    STAGE_V(0, 0);
    __syncthreads();
    for (int t = 0; t < 16; ++t) {
        const int cur = t & 1;
        if (t < 15) { STAGE_K(t + 1, cur ^ 1); STAGE_V(t + 1, cur ^ 1); }
        f32x4 acc[4];
        #pragma unroll
        for (int j = 0; j < 4; ++j) acc[j] = (f32x4){0.f, 0.f, 0.f, 0.f};
        #pragma unroll
        for (int kk = 0; kk < 2; ++kk)
            #pragma unroll
            for (int j = 0; j < 4; ++j) {
                int row = j * 16 + lr;
                bf16x8 bk2 = *(const bf16x8*)&Ks[cur][row * 64 + ((lk * 8 + kk * 32) ^ ((row & 7) * 8))];
                acc[j] = MFMA16(aq[kk], bk2, acc[j]);
            }
        // normalized bf16 P tile (per-wave LDS region; wave-coherent)
        #pragma unroll
        for (int j = 0; j < 4; ++j)
            #pragma unroll
            for (int rr = 0; rr < 4; ++rr) {
                int ql = lk * 4 + rr;
                float pv = __expf(SM_SCALE * acc[j][rr]) * inv[rr];
                Psw[ql * 64 + ((j * 16 + lr) ^ ((ql & 7) * 8))] = f2b(pv);
            }
        // PV MFMA from Psw / Vs
        #pragma unroll
        for (int kk = 0; kk < 2; ++kk) {
            bf16x8 pa = *(const bf16x8*)&Psw[lr * 64 + ((kk * 32 + lk * 8) ^ ((lr & 7) * 8))];
            #pragma unroll
            for (int j = 0; j < 4; ++j) {
                int row = j * 16 + lr;
                bf16x8 bv2 = *(const bf16x8*)&Vs[cur][row * 64 + ((kk * 32 + lk * 8) ^ ((row & 7) * 8))];
                occ[j] = MFMA16(pa, bv2, occ[j]);
            }
        }
        // emit attn rows from Psw as float4 pairs (coalesced: 8 lanes = 256B)
        float* Obt = Ob + t * 64;
        #pragma unroll
        for (int hh = 0; hh < 2; ++hh) {
            int rl = erow + hh * 8;
            bf16x8 p8 = *(const bf16x8*)&Psw[rl * 64 + ((eseg * 8) ^ ((rl & 7) * 8))];
            float4 o0 = make_float4(b2f((ushort_t)p8[0]), b2f((ushort_t)p8[1]),
                                    b2f((ushort_t)p8[2]), b2f((ushort_t)p8[3]));
            float4 o1 = make_float4(b2f((ushort_t)p8[4]), b2f((ushort_t)p8[5]),
                                    b2f((ushort_t)p8[6]), b2f((ushort_t)p8[7]));
            *(float4*)(Obt + (size_t)rl * SS + eseg * 8) = o0;
            *(float4*)(Obt + (size_t)rl * SS + eseg * 8 + 4) = o1;
        }
        __syncthreads();
    }

    #pragma unroll
    for (int j = 0; j < 4; ++j)
        #pragma unroll
        for (int rr = 0; rr < 4; ++rr)
            ctx[((size_t)b * LL + r0 + w * 16 + lk * 4 + rr) * NH + h * DKH + j * 16 + lr]
                = f2b(occ[j][rr]);
#undef STAGE_K
#undef STAGE_V
}

// ---------------------------------------------------------------------------
// Output projection: out[i][d] = sum_n ctx[i][n]*Wo2[d][n] + b_o[d]
// ---------------------------------------------------------------------------
__global__ __launch_bounds__(256) void out_gemm(
    const ushort_t* __restrict__ A, const ushort_t* __restrict__ B,
    const float* __restrict__ bias, float* __restrict__ C)
{
    __shared__ ushort_t As[128 * 64];
    __shared__ ushort_t Bs[64 * 64];
    const int p  = xcd_swz(blockIdx.x, gridDim.x);
    const int bm = (p >> 4) * 128;
    const int bn = (p & 15) * 64;
    const int tid = threadIdx.x;
    const int lane = tid & 63;
    const int w = tid >> 6;
    const int wr = w >> 1, wc = w & 1;
    const int lr = lane & 15, lk = lane >> 4;

    f32x4 acc[4][2];
    #pragma unroll
    for (int i = 0; i < 4; ++i)
        #pragma unroll
        for (int j = 0; j < 2; ++j)
            acc[i][j] = (f32x4){0.f, 0.f, 0.f, 0.f};

    for (int k0 = 0; k0 < 1024; k0 += 64) {
        #pragma unroll
        for (int pp = 0; pp < 4; ++pp) {
            int f = pp * 256 + tid;
            int row = f >> 3, seg = f & 7;
            int kb2 = (seg * 8) ^ ((row & 7) * 8);
            gload_lds16(A + (size_t)(bm + row) * 1024 + k0 + kb2,
                        (char*)As + ((pp * 256 + (w << 6)) << 4));
        }
        #pragma unroll
        for (int pp = 0; pp < 2; ++pp) {
            int f = pp * 256 + tid;
            int row = f >> 3, seg = f & 7;
            int kb2 = (seg * 8) ^ ((row & 7) * 8);
            gload_lds16(B + (size_t)(bn + row) * 1024 + k0 + kb2,
                        (char*)Bs + ((pp * 256 + (w << 6)) << 4));
        }
        __syncthreads();
        #pragma unroll
        for (int kk = 0; kk < 2; ++kk) {
            bf16x8 af[4], bfr[2];
            #pragma unroll
            for (int i = 0; i < 4; ++i) {
                int row = wr * 64 + i * 16 + lr;
                af[i] = *(const bf16x8*)&As[row * 64 + ((lk * 8 + kk * 32) ^ ((row & 7) * 8))];
            }
            #pragma unroll
            for (int j = 0; j < 2; ++j) {
                int row = wc * 32 + j * 16 + lr;
                bfr[j] = *(const bf16x8*)&Bs[row * 64 + ((lk * 8 + kk * 32) ^ ((row & 7) * 8))];
            }
            #pragma unroll
            for (int i = 0; i < 4; ++i)
                #pragma unroll
                for (int j = 0; j < 2; ++j)
                    acc[i][j] = MFMA16(af[i], bfr[j], acc[i][j]);
        }
        __syncthreads();
    }

    #pragma unroll
    for (int i = 0; i < 4; ++i)
        #pragma unroll
        for (int j = 0; j < 2; ++j)
            #pragma unroll
            for (int rr = 0; rr < 4; ++rr) {
                int row = bm + wr * 64 + i * 16 + lk * 4 + rr;
                int col = bn + wc * 32 + j * 16 + lr;
                C[(size_t)row * DM + col] = acc[i][j][rr] + bias[col];
            }
}

// ---------------------------------------------------------------------------
extern "C" void kernel_launch(void* const* d_in, const int* in_sizes, int n_in,
                              void* d_out, int out_size, void* d_ws, size_t ws_size,
                              hipStream_t stream)
{
    const float* queries = (const float*)d_in[0];
    const float* keys    = (const float*)d_in[1];
    const float* values  = (const float*)d_in[2];
    const float* gate    = (const float*)d_in[3];
    const float* W_q     = (const float*)d_in[4];
    const float* b_q     = (const float*)d_in[5];
    const float* W_k     = (const float*)d_in[6];
    const float* b_k     = (const float*)d_in[7];
    const float* W_v     = (const float*)d_in[8];
    const float* b_v     = (const float*)d_in[9];
    const float* W_o     = (const float*)d_in[10];
    const float* b_o     = (const float*)d_in[11];

    float* out  = (float*)d_out;                        // [B,L,DM]
    float* attn = out + (size_t)BB * LL * DM;           // [B,H,L,S]

    char* ws = (char*)d_ws;
    const size_t U = (size_t)8 << 20;
    ushort_t* Xq = (ushort_t*)(ws);
    ushort_t* Xk = (ushort_t*)(ws + 1 * U);
    ushort_t* Xv = (ushort_t*)(ws + 2 * U);
    ushort_t* Gq = (ushort_t*)(ws + 3 * U);
    ushort_t* Gk = (ushort_t*)(ws + 4 * U);
    ushort_t* Gv = (ushort_t*)(ws + 5 * U);
    ushort_t* Vt = (ushort_t*)(ws + 6 * U);
    const bool big = ws_size >= 9 * U + ((size_t)2 << 20);
    ushort_t *Qb, *Kb, *Wo2;
    if (big) { Qb = (ushort_t*)(ws + 7 * U); Kb = (ushort_t*)(ws + 8 * U); Wo2 = (ushort_t*)(ws + 9 * U); }
    else     { Qb = Xv; Kb = Gv; Wo2 = (ushort_t*)(ws + 7 * U); }
    ushort_t* ctx = Xq;     // Xq dead after Q-GEMM

    dim3 blk(256, 1, 1);
    prep_kernel<<<2048, blk, 0, stream>>>(queries, keys, values, gate,
                                          W_q, W_k, W_v, W_o,
                                          Xq, Xk, Xv, Gq, Gk, Gv, Wo2);
    if (big) {
        qkv_gemm<<<768, blk, 0, stream>>>(Xq, Gq, b_q, Xk, Gk, b_k,
                                          Xv, Gv, b_v, Qb, Kb, Vt, 0);
    } else {
        // Vt first (reads Xv,Gv), then Q/K merged writing into dead Xv/Gv slots
        qkv_gemm<<<256, blk, 0, stream>>>(Xq, Gq, b_q, Xk, Gk, b_k,
                                          Xv, Gv, b_v, Qb, Kb, Vt, 2);
        qkv_gemm<<<512, blk, 0, stream>>>(Xq, Gq, b_q, Xk, Gk, b_k,
                                          Xv, Gv, b_v, Qb, Kb, Vt, 1);
    }
    fused_attn_kernel<<<1024, blk, 0, stream>>>(Qb, Kb, Vt, attn, ctx);
    out_gemm<<<512, blk, 0, stream>>>(ctx, Wo2, b_o, out);
}